// Round 1
// baseline (442.521 us; speedup 1.0000x reference)
//
#include <hip/hip_runtime.h>

#define NN 50000
#define E0 800000
#define ET 850000          // E0 + NN self loops
#define EPS_BN 1e-5f
#define SLOPE 0.2f
#define NB_SCAN 49         // ceil(NN/1024)

__device__ __forceinline__ float lrelu(float v){ return v > 0.f ? v : SLOPE*v; }

// ---------------- BatchNorm stats ----------------
__global__ __launch_bounds__(256) void bn_stats(const float* __restrict__ x, float* __restrict__ stats){
  int n = blockIdx.x*256 + threadIdx.x;
  float s[4]={0,0,0,0}, q[4]={0,0,0,0};
  if (n < NN){
    float4 v = *reinterpret_cast<const float4*>(x + (size_t)n*4);
    s[0]=v.x; s[1]=v.y; s[2]=v.z; s[3]=v.w;
    q[0]=v.x*v.x; q[1]=v.y*v.y; q[2]=v.z*v.z; q[3]=v.w*v.w;
  }
  #pragma unroll
  for (int m=1;m<64;m<<=1){
    #pragma unroll
    for (int i=0;i<4;i++){ s[i]+=__shfl_xor(s[i],m); q[i]+=__shfl_xor(q[i],m); }
  }
  if ((threadIdx.x&63)==0){
    #pragma unroll
    for (int i=0;i<4;i++){ atomicAdd(&stats[i], s[i]); atomicAdd(&stats[4+i], q[i]); }
  }
}

// ---------------- CSR build ----------------
__global__ __launch_bounds__(256) void hist_dst(const int* __restrict__ ei, int* __restrict__ cnt){
  int e = blockIdx.x*256 + threadIdx.x;
  if (e >= ET) return;
  int dst = (e < E0) ? ei[E0 + e] : (e - E0);
  atomicAdd(&cnt[dst], 1);
}

__global__ __launch_bounds__(256) void scanA(const int* __restrict__ cnt, int* __restrict__ rowptr, int* __restrict__ bsum){
  __shared__ int lds[256];
  int tid = threadIdx.x;
  int base = blockIdx.x*1024 + tid*4;
  int v0 = (base+0 < NN) ? cnt[base+0] : 0;
  int v1 = (base+1 < NN) ? cnt[base+1] : 0;
  int v2 = (base+2 < NN) ? cnt[base+2] : 0;
  int v3 = (base+3 < NN) ? cnt[base+3] : 0;
  int tsum = v0+v1+v2+v3;
  int val = tsum;
  lds[tid] = val; __syncthreads();
  for (int off=1; off<256; off<<=1){
    int t = (tid>=off) ? lds[tid-off] : 0;
    __syncthreads();
    val += t; lds[tid] = val; __syncthreads();
  }
  int excl = val - tsum;
  if (base+0 < NN) rowptr[base+0] = excl;
  if (base+1 < NN) rowptr[base+1] = excl + v0;
  if (base+2 < NN) rowptr[base+2] = excl + v0 + v1;
  if (base+3 < NN) rowptr[base+3] = excl + v0 + v1 + v2;
  if (tid == 255) bsum[blockIdx.x] = val;
}

__global__ __launch_bounds__(64) void scanB(int* __restrict__ bsum){
  int i = threadIdx.x;
  int v = (i < NB_SCAN) ? bsum[i] : 0;
  int orig = v;
  #pragma unroll
  for (int off=1; off<64; off<<=1){
    int t = __shfl_up(v, off);
    if (i >= off) v += t;
  }
  if (i < NB_SCAN) bsum[i] = v - orig;   // exclusive
}

__global__ __launch_bounds__(256) void scanC(int* __restrict__ rowptr, const int* __restrict__ bsum){
  int add = bsum[blockIdx.x];
  int base = blockIdx.x*1024 + threadIdx.x*4;
  #pragma unroll
  for (int j=0;j<4;j++) if (base+j < NN) rowptr[base+j] += add;
  if (blockIdx.x==0 && threadIdx.x==0) rowptr[NN] = ET;
}

__global__ __launch_bounds__(256) void scatter_e(const int* __restrict__ ei, const int* __restrict__ rowptr,
                                                 int* __restrict__ fill, int* __restrict__ ssrc){
  int e = blockIdx.x*256 + threadIdx.x;
  if (e >= ET) return;
  int src, dst;
  if (e < E0){ src = ei[e]; dst = ei[E0+e]; } else { src = dst = e - E0; }
  int pos = rowptr[dst] + atomicAdd(&fill[dst], 1);
  ssrc[pos] = src;
}

// ---------------- node kernels ----------------
// IN small, OUT=128 (H=4, C=32). 2 nodes per 256-block; thread -> (node, oc).
template<int IN, bool BN>
__global__ __launch_bounds__(256) void node_big(
    const float* __restrict__ xin, const float* __restrict__ W,
    const float* __restrict__ asrc, const float* __restrict__ adst,
    const float* __restrict__ stats, const float* __restrict__ gamma, const float* __restrict__ beta,
    float* __restrict__ h, float* __restrict__ als, float* __restrict__ ald){
  int t = threadIdx.x;
  int n = blockIdx.x*2 + (t>>7);
  int oc = t & 127;
  float xv[IN];
  #pragma unroll
  for (int i=0;i<IN;i++) xv[i] = xin[(size_t)n*IN + i];
  if constexpr (BN){
    #pragma unroll
    for (int i=0;i<IN;i++){
      float mu  = stats[i]   * (1.0f/NN);
      float var = stats[4+i] * (1.0f/NN) - mu*mu;
      xv[i] = (xv[i]-mu) * rsqrtf(var + EPS_BN) * gamma[i] + beta[i];
    }
  }
  float hv = 0.f;
  #pragma unroll
  for (int i=0;i<IN;i++) hv += xv[i] * W[i*128 + oc];
  h[(size_t)n*128 + oc] = hv;
  int head = oc>>5, c = oc&31;
  float ps = hv * asrc[head*32 + c];
  float pd = hv * adst[head*32 + c];
  #pragma unroll
  for (int m=16;m>=1;m>>=1){ ps += __shfl_xor(ps,m); pd += __shfl_xor(pd,m); }
  if (c==0){ als[n*4 + head] = ps; ald[n*4 + head] = pd; }
}

// IN=128, OUT in {2,4}, H=1. One wave per node.
template<int OUT>
__global__ __launch_bounds__(256) void node_small(
    const float* __restrict__ xin, const float* __restrict__ W,
    const float* __restrict__ asrc, const float* __restrict__ adst,
    float* __restrict__ h, float* __restrict__ als, float* __restrict__ ald){
  int lane = threadIdx.x & 63;
  int n = blockIdx.x*4 + (threadIdx.x>>6);
  float2 xv = reinterpret_cast<const float2*>(xin + (size_t)n*128)[lane];
  float hv[OUT];
  #pragma unroll
  for (int oc=0; oc<OUT; oc++){
    float p = xv.x * W[(2*lane)*OUT + oc] + xv.y * W[(2*lane+1)*OUT + oc];
    #pragma unroll
    for (int m=1;m<64;m<<=1) p += __shfl_xor(p,m);
    hv[oc] = p;
  }
  if (lane==0){
    float as_=0.f, ad_=0.f;
    #pragma unroll
    for (int oc=0;oc<OUT;oc++){
      as_ += hv[oc]*asrc[oc]; ad_ += hv[oc]*adst[oc];
      h[(size_t)n*OUT + oc] = hv[oc];
    }
    als[n] = as_; ald[n] = ad_;
  }
}

// ---------------- edge kernels ----------------
// H=4, C=32 (128 channels). One wave per dst node; lane owns channels lane, lane+64.
template<bool RELU>
__global__ __launch_bounds__(256) void edge_big(
    const float* __restrict__ h, const float* __restrict__ als, const float* __restrict__ ald,
    const int* __restrict__ rowptr, const int* __restrict__ ssrc,
    const float* __restrict__ bias, float* __restrict__ out){
  int lane = threadIdx.x & 63;
  int dst = blockIdx.x*4 + (threadIdx.x>>6);
  int r0 = rowptr[dst], r1 = rowptr[dst+1];
  int deg = r1 - r0;
  const float4* als4 = reinterpret_cast<const float4*>(als);
  float4 adv = reinterpret_cast<const float4*>(ald)[dst];
  float mx0=-1e30f, mx1=-1e30f, mx2=-1e30f, mx3=-1e30f;
  for (int i=lane; i<deg; i+=64){
    int s = ssrc[r0+i];
    float4 av = als4[s];
    mx0 = fmaxf(mx0, lrelu(av.x+adv.x));
    mx1 = fmaxf(mx1, lrelu(av.y+adv.y));
    mx2 = fmaxf(mx2, lrelu(av.z+adv.z));
    mx3 = fmaxf(mx3, lrelu(av.w+adv.w));
  }
  #pragma unroll
  for (int m=1;m<64;m<<=1){
    mx0=fmaxf(mx0,__shfl_xor(mx0,m)); mx1=fmaxf(mx1,__shfl_xor(mx1,m));
    mx2=fmaxf(mx2,__shfl_xor(mx2,m)); mx3=fmaxf(mx3,__shfl_xor(mx3,m));
  }
  float sum0=0,sum1=0,sum2=0,sum3=0;
  float acc0=0.f, acc1=0.f;
  bool low = lane < 32;
  int c0 = lane, c1 = lane + 64;
  for (int base=0; base<deg; base+=64){
    int cnt = min(64, deg-base);
    float w0=0,w1=0,w2=0,w3=0; int src=0;
    if (lane < cnt){
      src = ssrc[r0+base+lane];
      float4 av = als4[src];
      w0 = expf(lrelu(av.x+adv.x)-mx0); sum0 += w0;
      w1 = expf(lrelu(av.y+adv.y)-mx1); sum1 += w1;
      w2 = expf(lrelu(av.z+adv.z)-mx2); sum2 += w2;
      w3 = expf(lrelu(av.w+adv.w)-mx3); sum3 += w3;
    }
    for (int i=0;i<cnt;i++){
      int si = __shfl(src, i);
      float v0=__shfl(w0,i), v1=__shfl(w1,i), v2=__shfl(w2,i), v3=__shfl(w3,i);
      const float* hp = h + (size_t)si*128;
      acc0 += (low ? v0 : v1) * hp[c0];
      acc1 += (low ? v2 : v3) * hp[c1];
    }
  }
  #pragma unroll
  for (int m=1;m<64;m<<=1){
    sum0+=__shfl_xor(sum0,m); sum1+=__shfl_xor(sum1,m);
    sum2+=__shfl_xor(sum2,m); sum3+=__shfl_xor(sum3,m);
  }
  float inv0 = 1.f/((low?sum0:sum1)+1e-16f);
  float inv1 = 1.f/((low?sum2:sum3)+1e-16f);
  float o0 = acc0*inv0 + bias[c0];
  float o1 = acc1*inv1 + bias[c1];
  if (RELU){ o0 = fmaxf(o0,0.f); o1 = fmaxf(o1,0.f); }
  out[(size_t)dst*128 + c0] = o0;
  out[(size_t)dst*128 + c1] = o1;
}

// H=1, C in {2,4}. One thread per dst node.
template<int C, bool RELU>
__global__ __launch_bounds__(256) void edge_small(
    const float* __restrict__ h, const float* __restrict__ als, const float* __restrict__ ald,
    const int* __restrict__ rowptr, const int* __restrict__ ssrc,
    const float* __restrict__ bias, float* __restrict__ out){
  int dst = blockIdx.x*256 + threadIdx.x;
  if (dst >= NN) return;
  int r0 = rowptr[dst], r1 = rowptr[dst+1];
  float adv = ald[dst];
  float mx = -1e30f;
  for (int i=r0; i<r1; i++){
    int s = ssrc[i];
    mx = fmaxf(mx, lrelu(als[s]+adv));
  }
  float sum = 0.f, acc[C];
  #pragma unroll
  for (int c=0;c<C;c++) acc[c]=0.f;
  for (int i=r0; i<r1; i++){
    int s = ssrc[i];
    float w = expf(lrelu(als[s]+adv)-mx);
    sum += w;
    #pragma unroll
    for (int c=0;c<C;c++) acc[c] += w * h[(size_t)s*C + c];
  }
  float inv = 1.f/(sum + 1e-16f);
  #pragma unroll
  for (int c=0;c<C;c++){
    float o = acc[c]*inv + bias[c];
    if (RELU) o = fmaxf(o,0.f);
    out[(size_t)dst*C + c] = o;
  }
}

// ---------------- launch ----------------
extern "C" void kernel_launch(void* const* d_in, const int* in_sizes, int n_in,
                              void* d_out, int out_size, void* d_ws, size_t ws_size,
                              hipStream_t stream) {
  const float* x     = (const float*)d_in[0];
  const int*   ei    = (const int*)  d_in[1];
  const float* gamma = (const float*)d_in[2];
  const float* beta  = (const float*)d_in[3];
  const float* w_e1  = (const float*)d_in[4];
  const float* as_e1 = (const float*)d_in[5];
  const float* ad_e1 = (const float*)d_in[6];
  const float* b_e1  = (const float*)d_in[7];
  const float* w_e3  = (const float*)d_in[8];
  const float* as_e3 = (const float*)d_in[9];
  const float* ad_e3 = (const float*)d_in[10];
  const float* b_e3  = (const float*)d_in[11];
  const float* w_d1  = (const float*)d_in[12];
  const float* as_d1 = (const float*)d_in[13];
  const float* ad_d1 = (const float*)d_in[14];
  const float* b_d1  = (const float*)d_in[15];
  const float* w_d3  = (const float*)d_in[16];
  const float* as_d3 = (const float*)d_in[17];
  const float* ad_d3 = (const float*)d_in[18];
  const float* b_d3  = (const float*)d_in[19];

  char* ws = (char*)d_ws;
  size_t off = 0;
  auto alloc = [&](size_t bytes)->void*{
    void* p = ws + off;
    off += (bytes + 255) & ~(size_t)255;
    return p;
  };
  float* stats  = (float*)alloc(32);
  int*   cnt    = (int*)  alloc((size_t)NN*4);
  int*   fill   = (int*)  alloc((size_t)NN*4);
  int*   rowptr = (int*)  alloc((size_t)(NN+1)*4);
  int*   bsum   = (int*)  alloc(256);
  int*   ssrc   = (int*)  alloc((size_t)ET*4);
  float* als    = (float*)alloc((size_t)NN*4*4);
  float* ald    = (float*)alloc((size_t)NN*4*4);
  float* hS     = (float*)alloc((size_t)NN*4*4);
  float* latC   = (float*)alloc((size_t)NN*2*4);
  float* hA     = (float*)alloc((size_t)NN*128*4);
  float* hB     = (float*)alloc((size_t)NN*128*4);

  hipMemsetAsync(stats, 0, 32, stream);
  hipMemsetAsync(cnt,  0, (size_t)NN*4, stream);
  hipMemsetAsync(fill, 0, (size_t)NN*4, stream);

  // BN stats + CSR build (graph fixed, rebuilt each call for determinism of the harness contract)
  bn_stats<<<(NN+255)/256, 256, 0, stream>>>(x, stats);
  hist_dst<<<(ET+255)/256, 256, 0, stream>>>(ei, cnt);
  scanA<<<NB_SCAN, 256, 0, stream>>>(cnt, rowptr, bsum);
  scanB<<<1, 64, 0, stream>>>(bsum);
  scanC<<<NB_SCAN, 256, 0, stream>>>(rowptr, bsum);
  scatter_e<<<(ET+255)/256, 256, 0, stream>>>(ei, rowptr, fill, ssrc);

  // Layer 1: BN + GAT(4->32x4, relu, concat)
  node_big<4, true><<<NN/2, 256, 0, stream>>>(x, w_e1, as_e1, ad_e1, stats, gamma, beta, hA, als, ald);
  edge_big<true><<<NN/4, 256, 0, stream>>>(hA, als, ald, rowptr, ssrc, b_e1, hB);
  // Layer 2: GAT(128->2, 1 head)
  node_small<2><<<NN/4, 256, 0, stream>>>(hB, w_e3, as_e3, ad_e3, hS, als, ald);
  edge_small<2, false><<<(NN+255)/256, 256, 0, stream>>>(hS, als, ald, rowptr, ssrc, b_e3, latC);
  // Layer 3: GAT(2->32x4, relu, concat)
  node_big<2, false><<<NN/2, 256, 0, stream>>>(latC, w_d1, as_d1, ad_d1, nullptr, nullptr, nullptr, hA, als, ald);
  edge_big<true><<<NN/4, 256, 0, stream>>>(hA, als, ald, rowptr, ssrc, b_d1, hB);
  // Layer 4: GAT(128->4, 1 head)
  node_small<4><<<NN/4, 256, 0, stream>>>(hB, w_d3, as_d3, ad_d3, hS, als, ald);
  edge_small<4, false><<<(NN+255)/256, 256, 0, stream>>>(hS, als, ald, rowptr, ssrc, b_d3, (float*)d_out);
}

// Round 2
// 270.851 us; speedup vs baseline: 1.6338x; 1.6338x over previous
//
#include <hip/hip_runtime.h>

#define NN 50000
#define E0 800000
#define ET 850000          // E0 + NN self loops
#define EPS_BN 1e-5f
#define SLOPE 0.2f
#define NB_SCAN 49         // ceil(NN/1024)

__device__ __forceinline__ float lrelu(float v){ return v > 0.f ? v : SLOPE*v; }

// ---------------- BatchNorm stats ----------------
__global__ __launch_bounds__(256) void bn_stats(const float* __restrict__ x, float* __restrict__ stats){
  int n = blockIdx.x*256 + threadIdx.x;
  float s[4]={0,0,0,0}, q[4]={0,0,0,0};
  if (n < NN){
    float4 v = *reinterpret_cast<const float4*>(x + (size_t)n*4);
    s[0]=v.x; s[1]=v.y; s[2]=v.z; s[3]=v.w;
    q[0]=v.x*v.x; q[1]=v.y*v.y; q[2]=v.z*v.z; q[3]=v.w*v.w;
  }
  #pragma unroll
  for (int m=1;m<64;m<<=1){
    #pragma unroll
    for (int i=0;i<4;i++){ s[i]+=__shfl_xor(s[i],m); q[i]+=__shfl_xor(q[i],m); }
  }
  if ((threadIdx.x&63)==0){
    #pragma unroll
    for (int i=0;i<4;i++){ atomicAdd(&stats[i], s[i]); atomicAdd(&stats[4+i], q[i]); }
  }
}

// ---------------- CSR build ----------------
__global__ __launch_bounds__(256) void hist_dst(const int* __restrict__ ei, int* __restrict__ cnt){
  int e = blockIdx.x*256 + threadIdx.x;
  if (e >= ET) return;
  int dst = (e < E0) ? ei[E0 + e] : (e - E0);
  atomicAdd(&cnt[dst], 1);
}

__global__ __launch_bounds__(256) void scanA(const int* __restrict__ cnt, int* __restrict__ rowptr, int* __restrict__ bsum){
  __shared__ int lds[256];
  int tid = threadIdx.x;
  int base = blockIdx.x*1024 + tid*4;
  int v0 = (base+0 < NN) ? cnt[base+0] : 0;
  int v1 = (base+1 < NN) ? cnt[base+1] : 0;
  int v2 = (base+2 < NN) ? cnt[base+2] : 0;
  int v3 = (base+3 < NN) ? cnt[base+3] : 0;
  int tsum = v0+v1+v2+v3;
  int val = tsum;
  lds[tid] = val; __syncthreads();
  for (int off=1; off<256; off<<=1){
    int t = (tid>=off) ? lds[tid-off] : 0;
    __syncthreads();
    val += t; lds[tid] = val; __syncthreads();
  }
  int excl = val - tsum;
  if (base+0 < NN) rowptr[base+0] = excl;
  if (base+1 < NN) rowptr[base+1] = excl + v0;
  if (base+2 < NN) rowptr[base+2] = excl + v0 + v1;
  if (base+3 < NN) rowptr[base+3] = excl + v0 + v1 + v2;
  if (tid == 255) bsum[blockIdx.x] = val;
}

__global__ __launch_bounds__(64) void scanB(int* __restrict__ bsum){
  int i = threadIdx.x;
  int v = (i < NB_SCAN) ? bsum[i] : 0;
  int orig = v;
  #pragma unroll
  for (int off=1; off<64; off<<=1){
    int t = __shfl_up(v, off);
    if (i >= off) v += t;
  }
  if (i < NB_SCAN) bsum[i] = v - orig;   // exclusive
}

__global__ __launch_bounds__(256) void scanC(int* __restrict__ rowptr, const int* __restrict__ bsum){
  int add = bsum[blockIdx.x];
  int base = blockIdx.x*1024 + threadIdx.x*4;
  #pragma unroll
  for (int j=0;j<4;j++) if (base+j < NN) rowptr[base+j] += add;
  if (blockIdx.x==0 && threadIdx.x==0) rowptr[NN] = ET;
}

__global__ __launch_bounds__(256) void scatter_e(const int* __restrict__ ei, const int* __restrict__ rowptr,
                                                 int* __restrict__ fill, int* __restrict__ ssrc){
  int e = blockIdx.x*256 + threadIdx.x;
  if (e >= ET) return;
  int src, dst;
  if (e < E0){ src = ei[e]; dst = ei[E0+e]; } else { src = dst = e - E0; }
  int pos = rowptr[dst] + atomicAdd(&fill[dst], 1);
  ssrc[pos] = src;
}

// ---------------- fold: precompute W @ a_src / W @ a_dst for layers 1 and 3 ----------------
// fold[0:16)  ws1[h*4+i]   fold[16:32) wd1[h*4+i]
// fold[32:40) ws3[h*2+i]   fold[40:48) wd3[h*2+i]
__global__ __launch_bounds__(64) void fold_k(
    const float* __restrict__ w_e1, const float* __restrict__ as_e1, const float* __restrict__ ad_e1,
    const float* __restrict__ w_d1, const float* __restrict__ as_d1, const float* __restrict__ ad_d1,
    float* __restrict__ fold){
  int t = threadIdx.x;
  if (t < 32){
    int idx = t & 15; int h = idx>>2; int i = idx&3;
    const float* a = (t<16) ? as_e1 : ad_e1;
    float s = 0.f;
    for (int c=0;c<32;c++) s += w_e1[i*128 + h*32 + c] * a[h*32 + c];
    fold[t] = s;
  } else if (t < 48){
    int idx = t - 32; int j = idx & 7; int h = j>>1; int i = j&1;
    const float* a = (idx<8) ? as_d1 : ad_d1;
    float s = 0.f;
    for (int c=0;c<32;c++) s += w_d1[i*128 + h*32 + c] * a[h*32 + c];
    fold[32 + idx] = s;
  }
}

// ---------------- node1: BN apply + layer-1 attention scores ----------------
__global__ __launch_bounds__(256) void node1(
    const float* __restrict__ x, const float* __restrict__ stats,
    const float* __restrict__ gamma, const float* __restrict__ beta,
    const float* __restrict__ fold,
    float* __restrict__ xbn, float* __restrict__ als1, float* __restrict__ ald1){
  int n = blockIdx.x*256 + threadIdx.x;
  if (n >= NN) return;
  float4 v = reinterpret_cast<const float4*>(x)[n];
  float xb[4] = {v.x, v.y, v.z, v.w};
  #pragma unroll
  for (int i=0;i<4;i++){
    float mu  = stats[i]   * (1.0f/NN);
    float var = stats[4+i] * (1.0f/NN) - mu*mu;
    xb[i] = (xb[i]-mu) * rsqrtf(var + EPS_BN) * gamma[i] + beta[i];
  }
  reinterpret_cast<float4*>(xbn)[n] = make_float4(xb[0],xb[1],xb[2],xb[3]);
  float4 s4, d4;
  float* sp = &s4.x; float* dp = &d4.x;
  #pragma unroll
  for (int h=0;h<4;h++){
    float s=0.f, d=0.f;
    #pragma unroll
    for (int i=0;i<4;i++){ s += xb[i]*fold[h*4+i]; d += xb[i]*fold[16+h*4+i]; }
    sp[h]=s; dp[h]=d;
  }
  reinterpret_cast<float4*>(als1)[n] = s4;
  reinterpret_cast<float4*>(ald1)[n] = d4;
}

// ---------------- edge aggregation in low-dim feature space ----------------
// 8-lane group per dst. NH heads, NC feature channels.
// EPI=1: write agg1[dst][NH*NC] normalized               (layer 1)
// EPI=2: latent = agg+bias; write latent + layer-3 scores (layer 2)
// EPI=3: write agg3[dst][NH*NC] normalized               (layer 3)
// EPI=4: write out = agg + bias                           (layer 4)
template<int NH, int NC, int EPI>
__global__ __launch_bounds__(256) void edge_agg(
    const float* __restrict__ feat, const float* __restrict__ als, const float* __restrict__ ald,
    const int* __restrict__ rowptr, const int* __restrict__ ssrc,
    const float* __restrict__ bias, const float* __restrict__ fold,
    float* __restrict__ out, float* __restrict__ als_out, float* __restrict__ ald_out){
  int dst = blockIdx.x*32 + (threadIdx.x>>3);
  int sub = threadIdx.x & 7;
  if (dst >= NN) return;
  int r0 = rowptr[dst], r1 = rowptr[dst+1];
  float adv[NH];
  if constexpr (NH==4){
    float4 t = reinterpret_cast<const float4*>(ald)[dst];
    adv[0]=t.x; adv[1]=t.y; adv[2]=t.z; adv[3]=t.w;
  } else adv[0] = ald[dst];

  float mx[NH];
  #pragma unroll
  for (int h=0;h<NH;h++) mx[h] = -1e30f;
  for (int i=r0+sub; i<r1; i+=8){
    int s = ssrc[i];
    if constexpr (NH==4){
      float4 a = reinterpret_cast<const float4*>(als)[s];
      mx[0]=fmaxf(mx[0], lrelu(a.x+adv[0]));
      mx[1]=fmaxf(mx[1], lrelu(a.y+adv[1]));
      mx[2]=fmaxf(mx[2], lrelu(a.z+adv[2]));
      mx[3]=fmaxf(mx[3], lrelu(a.w+adv[3]));
    } else {
      mx[0]=fmaxf(mx[0], lrelu(als[s]+adv[0]));
    }
  }
  #pragma unroll
  for (int m=1;m<8;m<<=1)
    #pragma unroll
    for (int h=0;h<NH;h++) mx[h]=fmaxf(mx[h], __shfl_xor(mx[h],m));

  float sum[NH]; float acc[NH][NC];
  #pragma unroll
  for (int h=0;h<NH;h++){ sum[h]=0.f;
    #pragma unroll
    for (int c=0;c<NC;c++) acc[h][c]=0.f; }

  for (int i=r0+sub; i<r1; i+=8){
    int s = ssrc[i];
    float f[NC];
    if constexpr (NC==4){
      float4 fv = reinterpret_cast<const float4*>(feat)[s];
      f[0]=fv.x; f[1]=fv.y; f[2]=fv.z; f[3]=fv.w;
    } else {
      float2 fv = reinterpret_cast<const float2*>(feat)[s];
      f[0]=fv.x; f[1]=fv.y;
    }
    if constexpr (NH==4){
      float4 a = reinterpret_cast<const float4*>(als)[s];
      float av[4] = {a.x,a.y,a.z,a.w};
      #pragma unroll
      for (int h=0;h<4;h++){
        float w = __expf(lrelu(av[h]+adv[h]) - mx[h]);
        sum[h] += w;
        #pragma unroll
        for (int c=0;c<NC;c++) acc[h][c] += w*f[c];
      }
    } else {
      float w = __expf(lrelu(als[s]+adv[0]) - mx[0]);
      sum[0] += w;
      #pragma unroll
      for (int c=0;c<NC;c++) acc[0][c] += w*f[c];
    }
  }
  #pragma unroll
  for (int m=1;m<8;m<<=1){
    #pragma unroll
    for (int h=0;h<NH;h++){
      sum[h] += __shfl_xor(sum[h],m);
      #pragma unroll
      for (int c=0;c<NC;c++) acc[h][c] += __shfl_xor(acc[h][c],m);
    }
  }
  if (sub != 0) return;
  float inv[NH];
  #pragma unroll
  for (int h=0;h<NH;h++) inv[h] = 1.f/(sum[h]+1e-16f);

  if constexpr (EPI==1){
    #pragma unroll
    for (int h=0;h<4;h++)
      reinterpret_cast<float4*>(out)[dst*4+h] =
        make_float4(acc[h][0]*inv[h], acc[h][1]*inv[h], acc[h][2]*inv[h], acc[h][3]*inv[h]);
  } else if constexpr (EPI==2){
    float l0 = acc[0][0]*inv[0] + bias[0];
    float l1 = acc[0][1]*inv[0] + bias[1];
    reinterpret_cast<float2*>(out)[dst] = make_float2(l0,l1);
    float4 s3, d3; float* sp=&s3.x; float* dp=&d3.x;
    #pragma unroll
    for (int h=0;h<4;h++){
      sp[h] = l0*fold[32+h*2+0] + l1*fold[32+h*2+1];
      dp[h] = l0*fold[40+h*2+0] + l1*fold[40+h*2+1];
    }
    reinterpret_cast<float4*>(als_out)[dst] = s3;
    reinterpret_cast<float4*>(ald_out)[dst] = d3;
  } else if constexpr (EPI==3){
    #pragma unroll
    for (int h=0;h<4;h++)
      reinterpret_cast<float2*>(out)[dst*4+h] =
        make_float2(acc[h][0]*inv[h], acc[h][1]*inv[h]);
  } else {
    reinterpret_cast<float4*>(out)[dst] =
      make_float4(acc[0][0]*inv[0]+bias[0], acc[0][1]*inv[0]+bias[1],
                  acc[0][2]*inv[0]+bias[2], acc[0][3]*inv[0]+bias[3]);
  }
}

// ---------------- post1: enc1 = relu(agg1 @ w_e1 + b) fused with layer-2 projection ----------------
__global__ __launch_bounds__(256) void post1(
    const float* __restrict__ agg1, const float* __restrict__ w_e1, const float* __restrict__ b_e1,
    const float* __restrict__ w_e3, const float* __restrict__ as_e3, const float* __restrict__ ad_e3,
    float* __restrict__ h2, float* __restrict__ als2, float* __restrict__ ald2){
  int lane = threadIdx.x & 63;
  int n = blockIdx.x*4 + (threadIdx.x>>6);
  int oc0 = lane, oc1 = lane + 64;
  int h0 = oc0>>5, h1 = oc1>>5;
  float4 a0 = reinterpret_cast<const float4*>(agg1)[n*4 + h0];
  float4 a1 = reinterpret_cast<const float4*>(agg1)[n*4 + h1];
  float e0 = b_e1[oc0] + a0.x*w_e1[0*128+oc0] + a0.y*w_e1[1*128+oc0]
                       + a0.z*w_e1[2*128+oc0] + a0.w*w_e1[3*128+oc0];
  float e1 = b_e1[oc1] + a1.x*w_e1[0*128+oc1] + a1.y*w_e1[1*128+oc1]
                       + a1.z*w_e1[2*128+oc1] + a1.w*w_e1[3*128+oc1];
  e0 = fmaxf(e0, 0.f); e1 = fmaxf(e1, 0.f);
  float p0 = e0*w_e3[oc0*2+0] + e1*w_e3[oc1*2+0];
  float p1 = e0*w_e3[oc0*2+1] + e1*w_e3[oc1*2+1];
  #pragma unroll
  for (int m=1;m<64;m<<=1){ p0 += __shfl_xor(p0,m); p1 += __shfl_xor(p1,m); }
  if (lane==0){
    reinterpret_cast<float2*>(h2)[n] = make_float2(p0,p1);
    als2[n] = p0*as_e3[0] + p1*as_e3[1];
    ald2[n] = p0*ad_e3[0] + p1*ad_e3[1];
  }
}

// ---------------- post3: dec1 = relu(agg3 @ w_d1 + b) fused with layer-4 projection ----------------
__global__ __launch_bounds__(256) void post3(
    const float* __restrict__ agg3, const float* __restrict__ w_d1, const float* __restrict__ b_d1,
    const float* __restrict__ w_d3, const float* __restrict__ as_d3, const float* __restrict__ ad_d3,
    float* __restrict__ h4, float* __restrict__ als4, float* __restrict__ ald4){
  int lane = threadIdx.x & 63;
  int n = blockIdx.x*4 + (threadIdx.x>>6);
  int oc0 = lane, oc1 = lane + 64;
  int h0 = oc0>>5, h1 = oc1>>5;
  float2 a0 = reinterpret_cast<const float2*>(agg3)[n*4 + h0];
  float2 a1 = reinterpret_cast<const float2*>(agg3)[n*4 + h1];
  float e0 = b_d1[oc0] + a0.x*w_d1[0*128+oc0] + a0.y*w_d1[1*128+oc0];
  float e1 = b_d1[oc1] + a1.x*w_d1[0*128+oc1] + a1.y*w_d1[1*128+oc1];
  e0 = fmaxf(e0, 0.f); e1 = fmaxf(e1, 0.f);
  float p[4];
  #pragma unroll
  for (int c=0;c<4;c++) p[c] = e0*w_d3[oc0*4+c] + e1*w_d3[oc1*4+c];
  #pragma unroll
  for (int m=1;m<64;m<<=1){
    #pragma unroll
    for (int c=0;c<4;c++) p[c] += __shfl_xor(p[c],m);
  }
  if (lane==0){
    reinterpret_cast<float4*>(h4)[n] = make_float4(p[0],p[1],p[2],p[3]);
    float s=0.f, d=0.f;
    #pragma unroll
    for (int c=0;c<4;c++){ s += p[c]*as_d3[c]; d += p[c]*ad_d3[c]; }
    als4[n] = s; ald4[n] = d;
  }
}

// ---------------- launch ----------------
extern "C" void kernel_launch(void* const* d_in, const int* in_sizes, int n_in,
                              void* d_out, int out_size, void* d_ws, size_t ws_size,
                              hipStream_t stream) {
  const float* x     = (const float*)d_in[0];
  const int*   ei    = (const int*)  d_in[1];
  const float* gamma = (const float*)d_in[2];
  const float* beta  = (const float*)d_in[3];
  const float* w_e1  = (const float*)d_in[4];
  const float* as_e1 = (const float*)d_in[5];
  const float* ad_e1 = (const float*)d_in[6];
  const float* b_e1  = (const float*)d_in[7];
  const float* w_e3  = (const float*)d_in[8];
  const float* as_e3 = (const float*)d_in[9];
  const float* ad_e3 = (const float*)d_in[10];
  const float* b_e3  = (const float*)d_in[11];
  const float* w_d1  = (const float*)d_in[12];
  const float* as_d1 = (const float*)d_in[13];
  const float* ad_d1 = (const float*)d_in[14];
  const float* b_d1  = (const float*)d_in[15];
  const float* w_d3  = (const float*)d_in[16];
  const float* as_d3 = (const float*)d_in[17];
  const float* ad_d3 = (const float*)d_in[18];
  const float* b_d3  = (const float*)d_in[19];

  char* ws = (char*)d_ws;
  size_t off = 0;
  auto alloc = [&](size_t bytes)->void*{
    void* p = ws + off;
    off += (bytes + 255) & ~(size_t)255;
    return p;
  };
  float* stats  = (float*)alloc(32);
  int*   cnt    = (int*)  alloc((size_t)NN*4);
  int*   fill   = (int*)  alloc((size_t)NN*4);
  int*   rowptr = (int*)  alloc((size_t)(NN+1)*4);
  int*   bsum   = (int*)  alloc(256);
  int*   ssrc   = (int*)  alloc((size_t)ET*4);
  float* fold   = (float*)alloc(64*4);
  float* xbn    = (float*)alloc((size_t)NN*4*4);
  float* als1   = (float*)alloc((size_t)NN*4*4);
  float* ald1   = (float*)alloc((size_t)NN*4*4);
  float* agg1   = (float*)alloc((size_t)NN*16*4);
  float* h2     = (float*)alloc((size_t)NN*2*4);
  float* als2   = (float*)alloc((size_t)NN*4);
  float* ald2   = (float*)alloc((size_t)NN*4);
  float* latent = (float*)alloc((size_t)NN*2*4);
  float* als3   = (float*)alloc((size_t)NN*4*4);
  float* ald3   = (float*)alloc((size_t)NN*4*4);
  float* agg3   = (float*)alloc((size_t)NN*8*4);
  float* h4     = (float*)alloc((size_t)NN*4*4);
  float* als4   = (float*)alloc((size_t)NN*4);
  float* ald4   = (float*)alloc((size_t)NN*4);

  hipMemsetAsync(stats, 0, 32, stream);
  hipMemsetAsync(cnt,  0, (size_t)NN*4, stream);
  hipMemsetAsync(fill, 0, (size_t)NN*4, stream);

  bn_stats<<<(NN+255)/256, 256, 0, stream>>>(x, stats);
  hist_dst<<<(ET+255)/256, 256, 0, stream>>>(ei, cnt);
  scanA<<<NB_SCAN, 256, 0, stream>>>(cnt, rowptr, bsum);
  scanB<<<1, 64, 0, stream>>>(bsum);
  scanC<<<NB_SCAN, 256, 0, stream>>>(rowptr, bsum);
  scatter_e<<<(ET+255)/256, 256, 0, stream>>>(ei, rowptr, fill, ssrc);
  fold_k<<<1, 64, 0, stream>>>(w_e1, as_e1, ad_e1, w_d1, as_d1, ad_d1, fold);

  const int AGG_BLOCKS = (NN*8 + 255)/256;

  // Layer 1: BN + scores, aggregate 4-dim xbn per head
  node1<<<(NN+255)/256, 256, 0, stream>>>(x, stats, gamma, beta, fold, xbn, als1, ald1);
  edge_agg<4,4,1><<<AGG_BLOCKS, 256, 0, stream>>>(xbn, als1, ald1, rowptr, ssrc, nullptr, nullptr, agg1, nullptr, nullptr);
  // post1: enc1 (in regs) -> h2 + layer-2 scores
  post1<<<NN/4, 256, 0, stream>>>(agg1, w_e1, b_e1, w_e3, as_e3, ad_e3, h2, als2, ald2);
  // Layer 2: aggregate 2-dim h2 -> latent, fused layer-3 scores
  edge_agg<1,2,2><<<AGG_BLOCKS, 256, 0, stream>>>(h2, als2, ald2, rowptr, ssrc, b_e3, fold, latent, als3, ald3);
  // Layer 3: aggregate 2-dim latent per head
  edge_agg<4,2,3><<<AGG_BLOCKS, 256, 0, stream>>>(latent, als3, ald3, rowptr, ssrc, nullptr, nullptr, agg3, nullptr, nullptr);
  // post3: dec1 (in regs) -> h4 + layer-4 scores
  post3<<<NN/4, 256, 0, stream>>>(agg3, w_d1, b_d1, w_d3, as_d3, ad_d3, h4, als4, ald4);
  // Layer 4: aggregate 4-dim h4 -> output + bias
  edge_agg<1,4,4><<<AGG_BLOCKS, 256, 0, stream>>>(h4, als4, ald4, rowptr, ssrc, b_d3, nullptr, (float*)d_out, nullptr, nullptr);
}

// Round 4
// 170.002 us; speedup vs baseline: 2.6030x; 1.5932x over previous
//
#include <hip/hip_runtime.h>

#define NN 50000
#define E0 800000
#define ET 850000          // E0 + NN self loops
#define EPS_BN 1e-5f
#define SLOPE 0.2f
#define NB_SCAN 49         // ceil(NN/1024)
#define NBP 32             // bn partial blocks

__device__ __forceinline__ float lrelu(float v){ return v > 0.f ? v : SLOPE*v; }

// ---------------- histogram of dst + BN partial sums (fused) ----------------
__global__ __launch_bounds__(256) void hist_bn(const int* __restrict__ ei, int* __restrict__ cnt,
                                               const float* __restrict__ x, float* __restrict__ part){
  int e = blockIdx.x*256 + threadIdx.x;
  if (e < ET){
    int dst = (e < E0) ? ei[E0 + e] : (e - E0);
    atomicAdd(&cnt[dst], 1);
  }
  if (blockIdx.x < NBP){
    float s[4]={0,0,0,0}, q[4]={0,0,0,0};
    for (int n = blockIdx.x*256 + threadIdx.x; n < NN; n += NBP*256){
      float4 v = reinterpret_cast<const float4*>(x)[n];
      s[0]+=v.x; s[1]+=v.y; s[2]+=v.z; s[3]+=v.w;
      q[0]+=v.x*v.x; q[1]+=v.y*v.y; q[2]+=v.z*v.z; q[3]+=v.w*v.w;
    }
    #pragma unroll
    for (int m=1;m<64;m<<=1){
      #pragma unroll
      for (int i=0;i<4;i++){ s[i]+=__shfl_xor(s[i],m); q[i]+=__shfl_xor(q[i],m); }
    }
    __shared__ float lds[4][8];
    int wid = threadIdx.x>>6, lane = threadIdx.x&63;
    if (lane==0){
      #pragma unroll
      for (int i=0;i<4;i++){ lds[wid][i]=s[i]; lds[wid][4+i]=q[i]; }
    }
    __syncthreads();
    if (threadIdx.x < 8){
      float p = lds[0][threadIdx.x]+lds[1][threadIdx.x]+lds[2][threadIdx.x]+lds[3][threadIdx.x];
      part[blockIdx.x*8 + threadIdx.x] = p;
    }
  }
}

// ---------------- BN finalize (scale/shift) + fold weights (one small block) ----------------
// sclsft[0..3]=scale, [4..7]=shift
// fold[0:16) ws1[h*4+i]  fold[16:32) wd1[h*4+i]  fold[32:40) ws3[h*2+i]  fold[40:48) wd3[h*2+i]
__global__ __launch_bounds__(128) void bnfin_fold(
    const float* __restrict__ part, const float* __restrict__ gamma, const float* __restrict__ beta,
    const float* __restrict__ w_e1, const float* __restrict__ as_e1, const float* __restrict__ ad_e1,
    const float* __restrict__ w_d1, const float* __restrict__ as_d1, const float* __restrict__ ad_d1,
    float* __restrict__ sclsft, float* __restrict__ fold){
  int t = threadIdx.x;
  if (t < 64){
    int ch = t&7, bslot = t>>3;
    float s = 0.f;
    for (int b=bslot; b<NBP; b+=8) s += part[b*8 + ch];
    s += __shfl_xor(s,8); s += __shfl_xor(s,16); s += __shfl_xor(s,32);
    float qv = __shfl(s, (t&3)+4);
    if (t < 4){
      float mu  = s*(1.0f/NN);
      float var = qv*(1.0f/NN) - mu*mu;
      float scl = rsqrtf(var + EPS_BN)*gamma[t];
      sclsft[t]   = scl;
      sclsft[4+t] = beta[t] - mu*scl;
    }
  } else {
    int u = t - 64;
    if (u < 32){
      int idx = u & 15; int h = idx>>2; int i = idx&3;
      const float* a = (u<16) ? as_e1 : ad_e1;
      float sum = 0.f;
      for (int c=0;c<32;c++) sum += w_e1[i*128 + h*32 + c] * a[h*32 + c];
      fold[u] = sum;
    } else if (u < 48){
      int idx = u - 32; int j = idx & 7; int h = j>>1; int i = j&1;
      const float* a = (idx<8) ? as_d1 : ad_d1;
      float sum = 0.f;
      for (int c=0;c<32;c++) sum += w_d1[i*128 + h*32 + c] * a[h*32 + c];
      fold[32 + idx] = sum;
    }
  }
}

// ---------------- CSR build ----------------
__global__ __launch_bounds__(256) void scanA(const int* __restrict__ cnt, int* __restrict__ rowptr, int* __restrict__ bsum){
  __shared__ int lds[256];
  int tid = threadIdx.x;
  int base = blockIdx.x*1024 + tid*4;
  int v0 = (base+0 < NN) ? cnt[base+0] : 0;
  int v1 = (base+1 < NN) ? cnt[base+1] : 0;
  int v2 = (base+2 < NN) ? cnt[base+2] : 0;
  int v3 = (base+3 < NN) ? cnt[base+3] : 0;
  int tsum = v0+v1+v2+v3;
  int val = tsum;
  lds[tid] = val; __syncthreads();
  for (int off=1; off<256; off<<=1){
    int t = (tid>=off) ? lds[tid-off] : 0;
    __syncthreads();
    val += t; lds[tid] = val; __syncthreads();
  }
  int excl = val - tsum;
  if (base+0 < NN) rowptr[base+0] = excl;
  if (base+1 < NN) rowptr[base+1] = excl + v0;
  if (base+2 < NN) rowptr[base+2] = excl + v0 + v1;
  if (base+3 < NN) rowptr[base+3] = excl + v0 + v1 + v2;
  if (tid == 255) bsum[blockIdx.x] = val;
}

__global__ __launch_bounds__(64) void scanB(int* __restrict__ bsum){
  int i = threadIdx.x;
  int v = (i < NB_SCAN) ? bsum[i] : 0;
  int orig = v;
  #pragma unroll
  for (int off=1; off<64; off<<=1){
    int t = __shfl_up(v, off);
    if (i >= off) v += t;
  }
  if (i < NB_SCAN) bsum[i] = v - orig;   // exclusive
}

__global__ __launch_bounds__(256) void scanC(int* __restrict__ rowptr, const int* __restrict__ bsum,
                                             int* __restrict__ cursor){
  int add = bsum[blockIdx.x];
  int base = blockIdx.x*1024 + threadIdx.x*4;
  #pragma unroll
  for (int j=0;j<4;j++) if (base+j < NN){
    int v = rowptr[base+j] + add;
    rowptr[base+j] = v;
    cursor[base+j] = v;
  }
  if (blockIdx.x==0 && threadIdx.x==0) rowptr[NN] = ET;
}

__global__ __launch_bounds__(256) void scatter_e(const int* __restrict__ ei,
                                                 int* __restrict__ cursor, int* __restrict__ ssrc){
  int e = blockIdx.x*256 + threadIdx.x;
  if (e >= ET) return;
  int src, dst;
  if (e < E0){ src = ei[e]; dst = ei[E0+e]; } else { src = dst = e - E0; }
  int pos = atomicAdd(&cursor[dst], 1);
  ssrc[pos] = src;
}

// ---------------- node1: BN apply + layer-1 scores, packed write ----------------
// pk1[n*8]: [0..3]=als1 per head, [4..7]=xbn. ald1[n]: float4.
__global__ __launch_bounds__(256) void node1(
    const float* __restrict__ x, const float* __restrict__ sclsft, const float* __restrict__ fold,
    float* __restrict__ pk1, float* __restrict__ ald1){
  int n = blockIdx.x*256 + threadIdx.x;
  if (n >= NN) return;
  float4 v = reinterpret_cast<const float4*>(x)[n];
  float xb[4] = {v.x, v.y, v.z, v.w};
  #pragma unroll
  for (int i=0;i<4;i++) xb[i] = xb[i]*sclsft[i] + sclsft[4+i];
  float4 s4, d4;
  float* sp = &s4.x; float* dp = &d4.x;
  #pragma unroll
  for (int h=0;h<4;h++){
    float s=0.f, d=0.f;
    #pragma unroll
    for (int i=0;i<4;i++){ s += xb[i]*fold[h*4+i]; d += xb[i]*fold[16+h*4+i]; }
    sp[h]=s; dp[h]=d;
  }
  reinterpret_cast<float4*>(pk1)[n*2+0] = s4;
  reinterpret_cast<float4*>(pk1)[n*2+1] = make_float4(xb[0],xb[1],xb[2],xb[3]);
  reinterpret_cast<float4*>(ald1)[n] = d4;
}

// ---------------- 4-head edge aggregation: 8 lanes/dst = 2 edge-slots x 4 heads ----------------
// pk stride 8: [head]=als, [4..]=feat(NC). out[dst][head][NC] normalized.
template<int NC>
__global__ __launch_bounds__(256) void eagg_h4(
    const float* __restrict__ pk, const float* __restrict__ ald,
    const int* __restrict__ rowptr, const int* __restrict__ ssrc,
    float* __restrict__ out){
  int dst = blockIdx.x*32 + (threadIdx.x>>3);
  int sub = threadIdx.x & 7;
  if (dst >= NN) return;
  int eslot = sub>>2, head = sub&3;
  int r0 = rowptr[dst], r1 = rowptr[dst+1];
  float adv = ald[(size_t)dst*4 + head];
  float sum = 0.f, acc[NC];
  #pragma unroll
  for (int c=0;c<NC;c++) acc[c]=0.f;
  for (int i=r0+eslot; i<r1; i+=2){
    int s = ssrc[i];
    const float* base = pk + (size_t)s*8;
    float w = __expf(lrelu(base[head] + adv));
    sum += w;
    if constexpr (NC==4){
      float4 f = *reinterpret_cast<const float4*>(base+4);
      acc[0]+=w*f.x; acc[1]+=w*f.y; acc[2]+=w*f.z; acc[3]+=w*f.w;
    } else {
      float2 f = *reinterpret_cast<const float2*>(base+4);
      acc[0]+=w*f.x; acc[1]+=w*f.y;
    }
  }
  sum += __shfl_xor(sum, 4);
  #pragma unroll
  for (int c=0;c<NC;c++) acc[c] += __shfl_xor(acc[c], 4);
  if (eslot==0){
    float inv = 1.f/(sum+1e-16f);
    if constexpr (NC==4){
      reinterpret_cast<float4*>(out)[(size_t)dst*4 + head] =
        make_float4(acc[0]*inv, acc[1]*inv, acc[2]*inv, acc[3]*inv);
    } else {
      reinterpret_cast<float2*>(out)[(size_t)dst*4 + head] =
        make_float2(acc[0]*inv, acc[1]*inv);
    }
  }
}

// ---------------- 1-head edge aggregation: 8 lanes/dst ----------------
// EPI=2 (layer2): pk2 stride 4 {h2.x,h2.y,als2,-}; writes pk3 {als3[4],lat[2],-,-} + ald3
// EPI=4 (layer4): pk4 stride 8 {als4,-,-,-,h4[4]}; writes d_out
template<int NC, int STRIDE, int AOFF, int FOFF, int EPI>
__global__ __launch_bounds__(256) void eagg_h1(
    const float* __restrict__ pk, const float* __restrict__ ald,
    const int* __restrict__ rowptr, const int* __restrict__ ssrc,
    const float* __restrict__ bias, const float* __restrict__ fold,
    float* __restrict__ out, float* __restrict__ ald_out){
  int dst = blockIdx.x*32 + (threadIdx.x>>3);
  int sub = threadIdx.x & 7;
  if (dst >= NN) return;
  int r0 = rowptr[dst], r1 = rowptr[dst+1];
  float adv = ald[dst];
  float sum = 0.f, acc[NC];
  #pragma unroll
  for (int c=0;c<NC;c++) acc[c]=0.f;
  for (int i=r0+sub; i<r1; i+=8){
    int s = ssrc[i];
    const float* base = pk + (size_t)s*STRIDE;
    float w = __expf(lrelu(base[AOFF] + adv));
    sum += w;
    if constexpr (NC==2){
      float2 f = *reinterpret_cast<const float2*>(base+FOFF);
      acc[0]+=w*f.x; acc[1]+=w*f.y;
    } else {
      float4 f = *reinterpret_cast<const float4*>(base+FOFF);
      acc[0]+=w*f.x; acc[1]+=w*f.y; acc[2]+=w*f.z; acc[3]+=w*f.w;
    }
  }
  #pragma unroll
  for (int m=1;m<8;m<<=1){
    sum += __shfl_xor(sum,m);
    #pragma unroll
    for (int c=0;c<NC;c++) acc[c] += __shfl_xor(acc[c],m);
  }
  if (sub != 0) return;
  float inv = 1.f/(sum+1e-16f);
  if constexpr (EPI==2){
    float l0 = acc[0]*inv + bias[0];
    float l1 = acc[1]*inv + bias[1];
    float4 s3, d3; float* sp=&s3.x; float* dp=&d3.x;
    #pragma unroll
    for (int h=0;h<4;h++){
      sp[h] = l0*fold[32+h*2+0] + l1*fold[32+h*2+1];
      dp[h] = l0*fold[40+h*2+0] + l1*fold[40+h*2+1];
    }
    reinterpret_cast<float4*>(out)[(size_t)dst*2] = s3;
    out[(size_t)dst*8+4] = l0;
    out[(size_t)dst*8+5] = l1;
    reinterpret_cast<float4*>(ald_out)[dst] = d3;
  } else {
    reinterpret_cast<float4*>(out)[dst] =
      make_float4(acc[0]*inv+bias[0], acc[1]*inv+bias[1],
                  acc[2]*inv+bias[2], acc[3]*inv+bias[3]);
  }
}

// ---------------- post1: enc1 = relu(agg1 @ w_e1 + b) fused with layer-2 projection ----------------
__global__ __launch_bounds__(256) void post1(
    const float* __restrict__ agg1, const float* __restrict__ w_e1, const float* __restrict__ b_e1,
    const float* __restrict__ w_e3, const float* __restrict__ as_e3, const float* __restrict__ ad_e3,
    float* __restrict__ pk2, float* __restrict__ ald2){
  int lane = threadIdx.x & 63;
  int n = blockIdx.x*4 + (threadIdx.x>>6);
  int oc0 = lane, oc1 = lane + 64;
  int h0 = oc0>>5, h1 = oc1>>5;
  float4 a0 = reinterpret_cast<const float4*>(agg1)[n*4 + h0];
  float4 a1 = reinterpret_cast<const float4*>(agg1)[n*4 + h1];
  float e0 = b_e1[oc0] + a0.x*w_e1[0*128+oc0] + a0.y*w_e1[1*128+oc0]
                       + a0.z*w_e1[2*128+oc0] + a0.w*w_e1[3*128+oc0];
  float e1 = b_e1[oc1] + a1.x*w_e1[0*128+oc1] + a1.y*w_e1[1*128+oc1]
                       + a1.z*w_e1[2*128+oc1] + a1.w*w_e1[3*128+oc1];
  e0 = fmaxf(e0, 0.f); e1 = fmaxf(e1, 0.f);
  float p0 = e0*w_e3[oc0*2+0] + e1*w_e3[oc1*2+0];
  float p1 = e0*w_e3[oc0*2+1] + e1*w_e3[oc1*2+1];
  #pragma unroll
  for (int m=1;m<64;m<<=1){ p0 += __shfl_xor(p0,m); p1 += __shfl_xor(p1,m); }
  if (lane==0){
    reinterpret_cast<float4*>(pk2)[n] =
      make_float4(p0, p1, p0*as_e3[0]+p1*as_e3[1], 0.f);
    ald2[n] = p0*ad_e3[0] + p1*ad_e3[1];
  }
}

// ---------------- post3: dec1 = relu(agg3 @ w_d1 + b) fused with layer-4 projection ----------------
__global__ __launch_bounds__(256) void post3(
    const float* __restrict__ agg3, const float* __restrict__ w_d1, const float* __restrict__ b_d1,
    const float* __restrict__ w_d3, const float* __restrict__ as_d3, const float* __restrict__ ad_d3,
    float* __restrict__ pk4, float* __restrict__ ald4){
  int lane = threadIdx.x & 63;
  int n = blockIdx.x*4 + (threadIdx.x>>6);
  int oc0 = lane, oc1 = lane + 64;
  int h0 = oc0>>5, h1 = oc1>>5;
  float2 a0 = reinterpret_cast<const float2*>(agg3)[n*4 + h0];
  float2 a1 = reinterpret_cast<const float2*>(agg3)[n*4 + h1];
  float e0 = b_d1[oc0] + a0.x*w_d1[0*128+oc0] + a0.y*w_d1[1*128+oc0];
  float e1 = b_d1[oc1] + a1.x*w_d1[0*128+oc1] + a1.y*w_d1[1*128+oc1];
  e0 = fmaxf(e0, 0.f); e1 = fmaxf(e1, 0.f);
  float p[4];
  #pragma unroll
  for (int c=0;c<4;c++) p[c] = e0*w_d3[oc0*4+c] + e1*w_d3[oc1*4+c];
  #pragma unroll
  for (int m=1;m<64;m<<=1){
    #pragma unroll
    for (int c=0;c<4;c++) p[c] += __shfl_xor(p[c],m);
  }
  if (lane==0){
    float s=0.f, d=0.f;
    #pragma unroll
    for (int c=0;c<4;c++){ s += p[c]*as_d3[c]; d += p[c]*ad_d3[c]; }
    pk4[(size_t)n*8] = s;
    reinterpret_cast<float4*>(pk4 + (size_t)n*8 + 4)[0] = make_float4(p[0],p[1],p[2],p[3]);
    ald4[n] = d;
  }
}

// ---------------- launch ----------------
extern "C" void kernel_launch(void* const* d_in, const int* in_sizes, int n_in,
                              void* d_out, int out_size, void* d_ws, size_t ws_size,
                              hipStream_t stream) {
  const float* x     = (const float*)d_in[0];
  const int*   ei    = (const int*)  d_in[1];
  const float* gamma = (const float*)d_in[2];
  const float* beta  = (const float*)d_in[3];
  const float* w_e1  = (const float*)d_in[4];
  const float* as_e1 = (const float*)d_in[5];
  const float* ad_e1 = (const float*)d_in[6];
  const float* b_e1  = (const float*)d_in[7];
  const float* w_e3  = (const float*)d_in[8];
  const float* as_e3 = (const float*)d_in[9];
  const float* ad_e3 = (const float*)d_in[10];
  const float* b_e3  = (const float*)d_in[11];
  const float* w_d1  = (const float*)d_in[12];
  const float* as_d1 = (const float*)d_in[13];
  const float* ad_d1 = (const float*)d_in[14];
  const float* b_d1  = (const float*)d_in[15];
  const float* w_d3  = (const float*)d_in[16];
  const float* as_d3 = (const float*)d_in[17];
  const float* ad_d3 = (const float*)d_in[18];
  const float* b_d3  = (const float*)d_in[19];

  char* ws = (char*)d_ws;
  size_t off = 0;
  auto alloc = [&](size_t bytes)->void*{
    void* p = ws + off;
    off += (bytes + 255) & ~(size_t)255;
    return p;
  };
  int*   cnt    = (int*)  alloc((size_t)NN*4);
  int*   rowptr = (int*)  alloc((size_t)(NN+1)*4);
  int*   cursor = (int*)  alloc((size_t)NN*4);
  int*   bsum   = (int*)  alloc(256);
  float* part   = (float*)alloc((size_t)NBP*8*4);
  float* sclsft = (float*)alloc(32);
  float* fold   = (float*)alloc(64*4);
  int*   ssrc   = (int*)  alloc((size_t)ET*4);
  float* pk1    = (float*)alloc((size_t)NN*8*4);
  float* ald1   = (float*)alloc((size_t)NN*4*4);
  float* agg1   = (float*)alloc((size_t)NN*16*4);
  float* pk2    = (float*)alloc((size_t)NN*4*4);
  float* ald2   = (float*)alloc((size_t)NN*4);
  float* pk3    = (float*)alloc((size_t)NN*8*4);
  float* ald3   = (float*)alloc((size_t)NN*4*4);
  float* agg3   = (float*)alloc((size_t)NN*8*4);
  float* pk4    = (float*)alloc((size_t)NN*8*4);
  float* ald4   = (float*)alloc((size_t)NN*4);

  (void)hipMemsetAsync(cnt, 0, (size_t)NN*4, stream);

  hist_bn<<<(ET+255)/256, 256, 0, stream>>>(ei, cnt, x, part);
  bnfin_fold<<<1, 128, 0, stream>>>(part, gamma, beta, w_e1, as_e1, ad_e1, w_d1, as_d1, ad_d1, sclsft, fold);
  scanA<<<NB_SCAN, 256, 0, stream>>>(cnt, rowptr, bsum);
  scanB<<<1, 64, 0, stream>>>(bsum);
  scanC<<<NB_SCAN, 256, 0, stream>>>(rowptr, bsum, cursor);
  scatter_e<<<(ET+255)/256, 256, 0, stream>>>(ei, cursor, ssrc);

  const int AGG_BLOCKS = (NN+31)/32;

  // Layer 1
  node1<<<(NN+255)/256, 256, 0, stream>>>(x, sclsft, fold, pk1, ald1);
  eagg_h4<4><<<AGG_BLOCKS, 256, 0, stream>>>(pk1, ald1, rowptr, ssrc, agg1);
  post1<<<NN/4, 256, 0, stream>>>(agg1, w_e1, b_e1, w_e3, as_e3, ad_e3, pk2, ald2);
  // Layer 2 (fused layer-3 score projection)
  eagg_h1<2,4,2,0,2><<<AGG_BLOCKS, 256, 0, stream>>>(pk2, ald2, rowptr, ssrc, b_e3, fold, pk3, ald3);
  // Layer 3
  eagg_h4<2><<<AGG_BLOCKS, 256, 0, stream>>>(pk3, ald3, rowptr, ssrc, agg3);
  post3<<<NN/4, 256, 0, stream>>>(agg3, w_d1, b_d1, w_d3, as_d3, ad_d3, pk4, ald4);
  // Layer 4
  eagg_h1<4,8,0,4,4><<<AGG_BLOCKS, 256, 0, stream>>>(pk4, ald4, rowptr, ssrc, b_d3, nullptr, (float*)d_out, nullptr);
}

// Round 5
// 161.150 us; speedup vs baseline: 2.7460x; 1.0549x over previous
//
#include <hip/hip_runtime.h>

#define NN 50000
#define E0 800000
#define ET 850000          // E0 + NN self loops
#define EPS_BN 1e-5f
#define SLOPE 0.2f
#define NB_SCAN 49         // ceil(NN/1024)
#define NBP 32             // bn partial blocks
#define NPART 8            // dst partitions for XCD-local scatter
#define PSZ 6250           // NN / NPART
#define EPB 2048           // edges per chunk in scatter
#define NCHUNK ((ET + EPB - 1) / EPB)

__device__ __forceinline__ float lrelu(float v){ return v > 0.f ? v : SLOPE*v; }

// ---------------- histogram of dst + BN partial sums (fused) ----------------
__global__ __launch_bounds__(256) void hist_bn(const int* __restrict__ ei, int* __restrict__ cnt,
                                               const float* __restrict__ x, float* __restrict__ part){
  int e = blockIdx.x*256 + threadIdx.x;
  if (e < ET){
    int dst = (e < E0) ? ei[E0 + e] : (e - E0);
    atomicAdd(&cnt[dst], 1);
  }
  if (blockIdx.x < NBP){
    float s[4]={0,0,0,0}, q[4]={0,0,0,0};
    for (int n = blockIdx.x*256 + threadIdx.x; n < NN; n += NBP*256){
      float4 v = reinterpret_cast<const float4*>(x)[n];
      s[0]+=v.x; s[1]+=v.y; s[2]+=v.z; s[3]+=v.w;
      q[0]+=v.x*v.x; q[1]+=v.y*v.y; q[2]+=v.z*v.z; q[3]+=v.w*v.w;
    }
    #pragma unroll
    for (int m=1;m<64;m<<=1){
      #pragma unroll
      for (int i=0;i<4;i++){ s[i]+=__shfl_xor(s[i],m); q[i]+=__shfl_xor(q[i],m); }
    }
    __shared__ float lds[4][8];
    int wid = threadIdx.x>>6, lane = threadIdx.x&63;
    if (lane==0){
      #pragma unroll
      for (int i=0;i<4;i++){ lds[wid][i]=s[i]; lds[wid][4+i]=q[i]; }
    }
    __syncthreads();
    if (threadIdx.x < 8){
      float p = lds[0][threadIdx.x]+lds[1][threadIdx.x]+lds[2][threadIdx.x]+lds[3][threadIdx.x];
      part[blockIdx.x*8 + threadIdx.x] = p;
    }
  }
}

// ---------------- BN finalize (scale/shift) + fold weights (one small block) ----------------
// sclsft[0..3]=scale, [4..7]=shift
// fold[0:16) ws1[h*4+i]  fold[16:32) wd1[h*4+i]  fold[32:40) ws3[h*2+i]  fold[40:48) wd3[h*2+i]
__global__ __launch_bounds__(128) void bnfin_fold(
    const float* __restrict__ part, const float* __restrict__ gamma, const float* __restrict__ beta,
    const float* __restrict__ w_e1, const float* __restrict__ as_e1, const float* __restrict__ ad_e1,
    const float* __restrict__ w_d1, const float* __restrict__ as_d1, const float* __restrict__ ad_d1,
    float* __restrict__ sclsft, float* __restrict__ fold){
  int t = threadIdx.x;
  if (t < 64){
    int ch = t&7, bslot = t>>3;
    float s = 0.f;
    for (int b=bslot; b<NBP; b+=8) s += part[b*8 + ch];
    s += __shfl_xor(s,8); s += __shfl_xor(s,16); s += __shfl_xor(s,32);
    float qv = __shfl(s, (t&3)+4);
    if (t < 4){
      float mu  = s*(1.0f/NN);
      float var = qv*(1.0f/NN) - mu*mu;
      float scl = rsqrtf(var + EPS_BN)*gamma[t];
      sclsft[t]   = scl;
      sclsft[4+t] = beta[t] - mu*scl;
    }
  } else {
    int u = t - 64;
    if (u < 32){
      int idx = u & 15; int h = idx>>2; int i = idx&3;
      const float* a = (u<16) ? as_e1 : ad_e1;
      float sum = 0.f;
      for (int c=0;c<32;c++) sum += w_e1[i*128 + h*32 + c] * a[h*32 + c];
      fold[u] = sum;
    } else if (u < 48){
      int idx = u - 32; int j = idx & 7; int h = j>>1; int i = j&1;
      const float* a = (idx<8) ? as_d1 : ad_d1;
      float sum = 0.f;
      for (int c=0;c<32;c++) sum += w_d1[i*128 + h*32 + c] * a[h*32 + c];
      fold[32 + idx] = sum;
    }
  }
}

// ---------------- CSR build ----------------
__global__ __launch_bounds__(256) void scanA(const int* __restrict__ cnt, int* __restrict__ rowptr, int* __restrict__ bsum){
  __shared__ int lds[256];
  int tid = threadIdx.x;
  int base = blockIdx.x*1024 + tid*4;
  int v0 = (base+0 < NN) ? cnt[base+0] : 0;
  int v1 = (base+1 < NN) ? cnt[base+1] : 0;
  int v2 = (base+2 < NN) ? cnt[base+2] : 0;
  int v3 = (base+3 < NN) ? cnt[base+3] : 0;
  int tsum = v0+v1+v2+v3;
  int val = tsum;
  lds[tid] = val; __syncthreads();
  for (int off=1; off<256; off<<=1){
    int t = (tid>=off) ? lds[tid-off] : 0;
    __syncthreads();
    val += t; lds[tid] = val; __syncthreads();
  }
  int excl = val - tsum;
  if (base+0 < NN) rowptr[base+0] = excl;
  if (base+1 < NN) rowptr[base+1] = excl + v0;
  if (base+2 < NN) rowptr[base+2] = excl + v0 + v1;
  if (base+3 < NN) rowptr[base+3] = excl + v0 + v1 + v2;
  if (tid == 255) bsum[blockIdx.x] = val;
}

__global__ __launch_bounds__(64) void scanB(int* __restrict__ bsum){
  int i = threadIdx.x;
  int v = (i < NB_SCAN) ? bsum[i] : 0;
  int orig = v;
  #pragma unroll
  for (int off=1; off<64; off<<=1){
    int t = __shfl_up(v, off);
    if (i >= off) v += t;
  }
  if (i < NB_SCAN) bsum[i] = v - orig;   // exclusive
}

__global__ __launch_bounds__(256) void scanC(int* __restrict__ rowptr, const int* __restrict__ bsum,
                                             int* __restrict__ cursor){
  int add = bsum[blockIdx.x];
  int base = blockIdx.x*1024 + threadIdx.x*4;
  #pragma unroll
  for (int j=0;j<4;j++) if (base+j < NN){
    int v = rowptr[base+j] + add;
    rowptr[base+j] = v;
    cursor[base+j] = v;
  }
  if (blockIdx.x==0 && threadIdx.x==0) rowptr[NN] = ET;
}

// ---------------- dst-range-partitioned scatter (XCD-local ssrc writes) ----------------
// blockIdx & 7 = partition (round-robin -> same XCD per partition),
// blockIdx >> 3 = edge chunk. Each ssrc cache line is then written by one XCD,
// so stores merge in its L2 instead of 64B-per-store HBM writebacks.
__global__ __launch_bounds__(256) void scatter_part(const int* __restrict__ ei,
                                                    int* __restrict__ cursor, int* __restrict__ ssrc){
  int part = blockIdx.x & (NPART-1);
  int chunk = blockIdx.x >> 3;
  int lo = part * PSZ;
  int hi = lo + PSZ;
  int base = chunk * EPB;
  int end = min(base + EPB, ET);
  for (int e = base + threadIdx.x; e < end; e += 256){
    int dst = (e < E0) ? ei[E0 + e] : (e - E0);
    if (dst >= lo && dst < hi){
      int src = (e < E0) ? ei[e] : dst;
      int pos = atomicAdd(&cursor[dst], 1);
      ssrc[pos] = src;
    }
  }
}

// ---------------- node1: BN apply + layer-1 scores, packed write ----------------
// pk1[n*8]: [0..3]=als1 per head, [4..7]=xbn. ald1[n]: float4.
__global__ __launch_bounds__(256) void node1(
    const float* __restrict__ x, const float* __restrict__ sclsft, const float* __restrict__ fold,
    float* __restrict__ pk1, float* __restrict__ ald1){
  int n = blockIdx.x*256 + threadIdx.x;
  if (n >= NN) return;
  float4 v = reinterpret_cast<const float4*>(x)[n];
  float xb[4] = {v.x, v.y, v.z, v.w};
  #pragma unroll
  for (int i=0;i<4;i++) xb[i] = xb[i]*sclsft[i] + sclsft[4+i];
  float4 s4, d4;
  float* sp = &s4.x; float* dp = &d4.x;
  #pragma unroll
  for (int h=0;h<4;h++){
    float s=0.f, d=0.f;
    #pragma unroll
    for (int i=0;i<4;i++){ s += xb[i]*fold[h*4+i]; d += xb[i]*fold[16+h*4+i]; }
    sp[h]=s; dp[h]=d;
  }
  reinterpret_cast<float4*>(pk1)[n*2+0] = s4;
  reinterpret_cast<float4*>(pk1)[n*2+1] = make_float4(xb[0],xb[1],xb[2],xb[3]);
  reinterpret_cast<float4*>(ald1)[n] = d4;
}

// ---------------- 4-head edge aggregation: 8 lanes/dst = 2 edge-slots x 4 heads ----------------
// pk stride 8: [head]=als, [4..]=feat(NC). out[dst][head][NC] normalized.
template<int NC>
__global__ __launch_bounds__(256) void eagg_h4(
    const float* __restrict__ pk, const float* __restrict__ ald,
    const int* __restrict__ rowptr, const int* __restrict__ ssrc,
    float* __restrict__ out){
  int dst = blockIdx.x*32 + (threadIdx.x>>3);
  int sub = threadIdx.x & 7;
  if (dst >= NN) return;
  int eslot = sub>>2, head = sub&3;
  int r0 = rowptr[dst], r1 = rowptr[dst+1];
  float adv = ald[(size_t)dst*4 + head];
  float sum = 0.f, acc[NC];
  #pragma unroll
  for (int c=0;c<NC;c++) acc[c]=0.f;
  for (int i=r0+eslot; i<r1; i+=2){
    int s = ssrc[i];
    const float* base = pk + (size_t)s*8;
    float w = __expf(lrelu(base[head] + adv));
    sum += w;
    if constexpr (NC==4){
      float4 f = *reinterpret_cast<const float4*>(base+4);
      acc[0]+=w*f.x; acc[1]+=w*f.y; acc[2]+=w*f.z; acc[3]+=w*f.w;
    } else {
      float2 f = *reinterpret_cast<const float2*>(base+4);
      acc[0]+=w*f.x; acc[1]+=w*f.y;
    }
  }
  sum += __shfl_xor(sum, 4);
  #pragma unroll
  for (int c=0;c<NC;c++) acc[c] += __shfl_xor(acc[c], 4);
  if (eslot==0){
    float inv = 1.f/(sum+1e-16f);
    if constexpr (NC==4){
      reinterpret_cast<float4*>(out)[(size_t)dst*4 + head] =
        make_float4(acc[0]*inv, acc[1]*inv, acc[2]*inv, acc[3]*inv);
    } else {
      reinterpret_cast<float2*>(out)[(size_t)dst*4 + head] =
        make_float2(acc[0]*inv, acc[1]*inv);
    }
  }
}

// ---------------- 1-head edge aggregation: 8 lanes/dst ----------------
// EPI=2 (layer2): pk2 stride 4 {h2.x,h2.y,als2,-}; writes pk3 {als3[4],lat[2],-,-} + ald3
// EPI=4 (layer4): pk4 stride 8 {als4,-,-,-,h4[4]}; writes d_out
template<int NC, int STRIDE, int AOFF, int FOFF, int EPI>
__global__ __launch_bounds__(256) void eagg_h1(
    const float* __restrict__ pk, const float* __restrict__ ald,
    const int* __restrict__ rowptr, const int* __restrict__ ssrc,
    const float* __restrict__ bias, const float* __restrict__ fold,
    float* __restrict__ out, float* __restrict__ ald_out){
  int dst = blockIdx.x*32 + (threadIdx.x>>3);
  int sub = threadIdx.x & 7;
  if (dst >= NN) return;
  int r0 = rowptr[dst], r1 = rowptr[dst+1];
  float adv = ald[dst];
  float sum = 0.f, acc[NC];
  #pragma unroll
  for (int c=0;c<NC;c++) acc[c]=0.f;
  for (int i=r0+sub; i<r1; i+=8){
    int s = ssrc[i];
    const float* base = pk + (size_t)s*STRIDE;
    float w = __expf(lrelu(base[AOFF] + adv));
    sum += w;
    if constexpr (NC==2){
      float2 f = *reinterpret_cast<const float2*>(base+FOFF);
      acc[0]+=w*f.x; acc[1]+=w*f.y;
    } else {
      float4 f = *reinterpret_cast<const float4*>(base+FOFF);
      acc[0]+=w*f.x; acc[1]+=w*f.y; acc[2]+=w*f.z; acc[3]+=w*f.w;
    }
  }
  #pragma unroll
  for (int m=1;m<8;m<<=1){
    sum += __shfl_xor(sum,m);
    #pragma unroll
    for (int c=0;c<NC;c++) acc[c] += __shfl_xor(acc[c],m);
  }
  if (sub != 0) return;
  float inv = 1.f/(sum+1e-16f);
  if constexpr (EPI==2){
    float l0 = acc[0]*inv + bias[0];
    float l1 = acc[1]*inv + bias[1];
    float4 s3, d3; float* sp=&s3.x; float* dp=&d3.x;
    #pragma unroll
    for (int h=0;h<4;h++){
      sp[h] = l0*fold[32+h*2+0] + l1*fold[32+h*2+1];
      dp[h] = l0*fold[40+h*2+0] + l1*fold[40+h*2+1];
    }
    reinterpret_cast<float4*>(out)[(size_t)dst*2] = s3;
    out[(size_t)dst*8+4] = l0;
    out[(size_t)dst*8+5] = l1;
    reinterpret_cast<float4*>(ald_out)[dst] = d3;
  } else {
    reinterpret_cast<float4*>(out)[dst] =
      make_float4(acc[0]*inv+bias[0], acc[1]*inv+bias[1],
                  acc[2]*inv+bias[2], acc[3]*inv+bias[3]);
  }
}

// ---------------- post1: enc1 = relu(agg1 @ w_e1 + b) fused with layer-2 projection ----------------
__global__ __launch_bounds__(256) void post1(
    const float* __restrict__ agg1, const float* __restrict__ w_e1, const float* __restrict__ b_e1,
    const float* __restrict__ w_e3, const float* __restrict__ as_e3, const float* __restrict__ ad_e3,
    float* __restrict__ pk2, float* __restrict__ ald2){
  int lane = threadIdx.x & 63;
  int n = blockIdx.x*4 + (threadIdx.x>>6);
  int oc0 = lane, oc1 = lane + 64;
  int h0 = oc0>>5, h1 = oc1>>5;
  float4 a0 = reinterpret_cast<const float4*>(agg1)[n*4 + h0];
  float4 a1 = reinterpret_cast<const float4*>(agg1)[n*4 + h1];
  float e0 = b_e1[oc0] + a0.x*w_e1[0*128+oc0] + a0.y*w_e1[1*128+oc0]
                       + a0.z*w_e1[2*128+oc0] + a0.w*w_e1[3*128+oc0];
  float e1 = b_e1[oc1] + a1.x*w_e1[0*128+oc1] + a1.y*w_e1[1*128+oc1]
                       + a1.z*w_e1[2*128+oc1] + a1.w*w_e1[3*128+oc1];
  e0 = fmaxf(e0, 0.f); e1 = fmaxf(e1, 0.f);
  float p0 = e0*w_e3[oc0*2+0] + e1*w_e3[oc1*2+0];
  float p1 = e0*w_e3[oc0*2+1] + e1*w_e3[oc1*2+1];
  #pragma unroll
  for (int m=1;m<64;m<<=1){ p0 += __shfl_xor(p0,m); p1 += __shfl_xor(p1,m); }
  if (lane==0){
    reinterpret_cast<float4*>(pk2)[n] =
      make_float4(p0, p1, p0*as_e3[0]+p1*as_e3[1], 0.f);
    ald2[n] = p0*ad_e3[0] + p1*ad_e3[1];
  }
}

// ---------------- post3: dec1 = relu(agg3 @ w_d1 + b) fused with layer-4 projection ----------------
__global__ __launch_bounds__(256) void post3(
    const float* __restrict__ agg3, const float* __restrict__ w_d1, const float* __restrict__ b_d1,
    const float* __restrict__ w_d3, const float* __restrict__ as_d3, const float* __restrict__ ad_d3,
    float* __restrict__ pk4, float* __restrict__ ald4){
  int lane = threadIdx.x & 63;
  int n = blockIdx.x*4 + (threadIdx.x>>6);
  int oc0 = lane, oc1 = lane + 64;
  int h0 = oc0>>5, h1 = oc1>>5;
  float2 a0 = reinterpret_cast<const float2*>(agg3)[n*4 + h0];
  float2 a1 = reinterpret_cast<const float2*>(agg3)[n*4 + h1];
  float e0 = b_d1[oc0] + a0.x*w_d1[0*128+oc0] + a0.y*w_d1[1*128+oc0];
  float e1 = b_d1[oc1] + a1.x*w_d1[0*128+oc1] + a1.y*w_d1[1*128+oc1];
  e0 = fmaxf(e0, 0.f); e1 = fmaxf(e1, 0.f);
  float p[4];
  #pragma unroll
  for (int c=0;c<4;c++) p[c] = e0*w_d3[oc0*4+c] + e1*w_d3[oc1*4+c];
  #pragma unroll
  for (int m=1;m<64;m<<=1){
    #pragma unroll
    for (int c=0;c<4;c++) p[c] += __shfl_xor(p[c],m);
  }
  if (lane==0){
    float s=0.f, d=0.f;
    #pragma unroll
    for (int c=0;c<4;c++){ s += p[c]*as_d3[c]; d += p[c]*ad_d3[c]; }
    pk4[(size_t)n*8] = s;
    reinterpret_cast<float4*>(pk4 + (size_t)n*8 + 4)[0] = make_float4(p[0],p[1],p[2],p[3]);
    ald4[n] = d;
  }
}

// ---------------- launch ----------------
extern "C" void kernel_launch(void* const* d_in, const int* in_sizes, int n_in,
                              void* d_out, int out_size, void* d_ws, size_t ws_size,
                              hipStream_t stream) {
  const float* x     = (const float*)d_in[0];
  const int*   ei    = (const int*)  d_in[1];
  const float* gamma = (const float*)d_in[2];
  const float* beta  = (const float*)d_in[3];
  const float* w_e1  = (const float*)d_in[4];
  const float* as_e1 = (const float*)d_in[5];
  const float* ad_e1 = (const float*)d_in[6];
  const float* b_e1  = (const float*)d_in[7];
  const float* w_e3  = (const float*)d_in[8];
  const float* as_e3 = (const float*)d_in[9];
  const float* ad_e3 = (const float*)d_in[10];
  const float* b_e3  = (const float*)d_in[11];
  const float* w_d1  = (const float*)d_in[12];
  const float* as_d1 = (const float*)d_in[13];
  const float* ad_d1 = (const float*)d_in[14];
  const float* b_d1  = (const float*)d_in[15];
  const float* w_d3  = (const float*)d_in[16];
  const float* as_d3 = (const float*)d_in[17];
  const float* ad_d3 = (const float*)d_in[18];
  const float* b_d3  = (const float*)d_in[19];

  char* ws = (char*)d_ws;
  size_t off = 0;
  auto alloc = [&](size_t bytes)->void*{
    void* p = ws + off;
    off += (bytes + 255) & ~(size_t)255;
    return p;
  };
  int*   cnt    = (int*)  alloc((size_t)NN*4);
  int*   rowptr = (int*)  alloc((size_t)(NN+1)*4);
  int*   cursor = (int*)  alloc((size_t)NN*4);
  int*   bsum   = (int*)  alloc(256);
  float* part   = (float*)alloc((size_t)NBP*8*4);
  float* sclsft = (float*)alloc(32);
  float* fold   = (float*)alloc(64*4);
  int*   ssrc   = (int*)  alloc((size_t)ET*4);
  float* pk1    = (float*)alloc((size_t)NN*8*4);
  float* ald1   = (float*)alloc((size_t)NN*4*4);
  float* agg1   = (float*)alloc((size_t)NN*16*4);
  float* pk2    = (float*)alloc((size_t)NN*4*4);
  float* ald2   = (float*)alloc((size_t)NN*4);
  float* pk3    = (float*)alloc((size_t)NN*8*4);
  float* ald3   = (float*)alloc((size_t)NN*4*4);
  float* agg3   = (float*)alloc((size_t)NN*8*4);
  float* pk4    = (float*)alloc((size_t)NN*8*4);
  float* ald4   = (float*)alloc((size_t)NN*4);

  (void)hipMemsetAsync(cnt, 0, (size_t)NN*4, stream);

  hist_bn<<<(ET+255)/256, 256, 0, stream>>>(ei, cnt, x, part);
  bnfin_fold<<<1, 128, 0, stream>>>(part, gamma, beta, w_e1, as_e1, ad_e1, w_d1, as_d1, ad_d1, sclsft, fold);
  scanA<<<NB_SCAN, 256, 0, stream>>>(cnt, rowptr, bsum);
  scanB<<<1, 64, 0, stream>>>(bsum);
  scanC<<<NB_SCAN, 256, 0, stream>>>(rowptr, bsum, cursor);
  scatter_part<<<NCHUNK*NPART, 256, 0, stream>>>(ei, cursor, ssrc);

  const int AGG_BLOCKS = (NN+31)/32;

  // Layer 1
  node1<<<(NN+255)/256, 256, 0, stream>>>(x, sclsft, fold, pk1, ald1);
  eagg_h4<4><<<AGG_BLOCKS, 256, 0, stream>>>(pk1, ald1, rowptr, ssrc, agg1);
  post1<<<NN/4, 256, 0, stream>>>(agg1, w_e1, b_e1, w_e3, as_e3, ad_e3, pk2, ald2);
  // Layer 2 (fused layer-3 score projection)
  eagg_h1<2,4,2,0,2><<<AGG_BLOCKS, 256, 0, stream>>>(pk2, ald2, rowptr, ssrc, b_e3, fold, pk3, ald3);
  // Layer 3
  eagg_h4<2><<<AGG_BLOCKS, 256, 0, stream>>>(pk3, ald3, rowptr, ssrc, agg3);
  post3<<<NN/4, 256, 0, stream>>>(agg3, w_d1, b_d1, w_d3, as_d3, ad_d3, pk4, ald4);
  // Layer 4
  eagg_h1<4,8,0,4,4><<<AGG_BLOCKS, 256, 0, stream>>>(pk4, ald4, rowptr, ssrc, b_d3, nullptr, (float*)d_out, nullptr);
}

// Round 6
// 126.351 us; speedup vs baseline: 3.5023x; 1.2754x over previous
//
#include <hip/hip_runtime.h>

#define NN 50000
#define E0 800000
#define ET 850000          // E0 + NN self loops
#define EPS_BN 1e-5f
#define SLOPE 0.2f
#define NBP 32             // bn partial blocks
#define EPC 2048           // edges per chunk
#define NCH 416            // ceil(ET/EPC)
#define PBITS 10
#define NP 49              // partitions = ceil(NN / 1024)
#define SCN (NP*NCH)       // 20384 scan elements

__device__ __forceinline__ float lrelu(float v){ return v > 0.f ? v : SLOPE*v; }

// ---------------- K0: per-chunk partition histogram + BN partials ----------------
__global__ __launch_bounds__(256) void chunk_hist_bn(const int* __restrict__ ei, int* __restrict__ chunkcnt,
                                                     const float* __restrict__ x, float* __restrict__ part){
  __shared__ int cc[NP];
  for (int i=threadIdx.x; i<NP; i+=256) cc[i]=0;
  __syncthreads();
  int base = blockIdx.x*EPC;
  int end = min(base+EPC, ET);
  for (int e = base+threadIdx.x; e < end; e += 256){
    int dst = (e < E0) ? ei[E0 + e] : (e - E0);
    atomicAdd(&cc[dst>>PBITS], 1);
  }
  __syncthreads();
  for (int i=threadIdx.x; i<NP; i+=256) chunkcnt[blockIdx.x*NP + i] = cc[i];

  if (blockIdx.x < NBP){
    float s[4]={0,0,0,0}, q[4]={0,0,0,0};
    for (int n = blockIdx.x*256 + threadIdx.x; n < NN; n += NBP*256){
      float4 v = reinterpret_cast<const float4*>(x)[n];
      s[0]+=v.x; s[1]+=v.y; s[2]+=v.z; s[3]+=v.w;
      q[0]+=v.x*v.x; q[1]+=v.y*v.y; q[2]+=v.z*v.z; q[3]+=v.w*v.w;
    }
    #pragma unroll
    for (int m=1;m<64;m<<=1){
      #pragma unroll
      for (int i=0;i<4;i++){ s[i]+=__shfl_xor(s[i],m); q[i]+=__shfl_xor(q[i],m); }
    }
    __shared__ float lds[4][8];
    int wid = threadIdx.x>>6, lane = threadIdx.x&63;
    if (lane==0){
      #pragma unroll
      for (int i=0;i<4;i++){ lds[wid][i]=s[i]; lds[wid][4+i]=q[i]; }
    }
    __syncthreads();
    if (threadIdx.x < 8){
      float p = lds[0][threadIdx.x]+lds[1][threadIdx.x]+lds[2][threadIdx.x]+lds[3][threadIdx.x];
      part[blockIdx.x*8 + threadIdx.x] = p;
    }
  }
}

// ---------------- K1: scan of chunk counts (partition-major) + BN finalize + weight fold ----------------
// pofs[ch*NP+p] = exclusive offset of (chunk ch, partition p) run in pedge.
// Partition p's global start = pofs[0*NP+p] = pofs[p].
// sclsft[0..3]=scale, [4..7]=shift
// fold[0:16) ws1[h*4+i]  fold[16:32) wd1[h*4+i]  fold[32:40) ws3[h*2+i]  fold[40:48) wd3[h*2+i]
__global__ __launch_bounds__(1024) void scan_fold(
    const int* __restrict__ chunkcnt, int* __restrict__ pofs,
    const float* __restrict__ part, const float* __restrict__ gamma, const float* __restrict__ beta,
    const float* __restrict__ w_e1, const float* __restrict__ as_e1, const float* __restrict__ ad_e1,
    const float* __restrict__ w_d1, const float* __restrict__ as_d1, const float* __restrict__ ad_d1,
    float* __restrict__ sclsft, float* __restrict__ fold){
  __shared__ int wsum[1024];
  int t = threadIdx.x;
  const int PER = (SCN + 1023)/1024;   // 20
  int vals[PER];
  int mysum = 0;
  #pragma unroll
  for (int k=0;k<PER;k++){
    int idx = t*PER + k;
    int v = 0;
    if (idx < SCN){ int p = idx/NCH, ch = idx - p*NCH; v = chunkcnt[ch*NP + p]; }
    vals[k] = v; mysum += v;
  }
  wsum[t] = mysum; __syncthreads();
  int val = mysum;
  for (int off=1; off<1024; off<<=1){
    int tmp = (t>=off) ? wsum[t-off] : 0;
    __syncthreads();
    val += tmp; wsum[t] = val; __syncthreads();
  }
  int run = val - mysum;   // exclusive prefix
  #pragma unroll
  for (int k=0;k<PER;k++){
    int idx = t*PER + k;
    if (idx < SCN){ int p = idx/NCH, ch = idx - p*NCH; pofs[ch*NP + p] = run; }
    run += vals[k];
  }

  // BN finalize (wave 0) + fold (wave 1)
  if (t < 64){
    int ch = t&7, bslot = t>>3;
    float s = 0.f;
    for (int b=bslot; b<NBP; b+=8) s += part[b*8 + ch];
    s += __shfl_xor(s,8); s += __shfl_xor(s,16); s += __shfl_xor(s,32);
    float qv = __shfl(s, (t&3)+4);
    if (t < 4){
      float mu  = s*(1.0f/NN);
      float var = qv*(1.0f/NN) - mu*mu;
      float scl = rsqrtf(var + EPS_BN)*gamma[t];
      sclsft[t]   = scl;
      sclsft[4+t] = beta[t] - mu*scl;
    }
  } else if (t < 128){
    int u = t - 64;
    if (u < 32){
      int idx = u & 15; int h = idx>>2; int i = idx&3;
      const float* a = (u<16) ? as_e1 : ad_e1;
      float sum = 0.f;
      for (int c=0;c<32;c++) sum += w_e1[i*128 + h*32 + c] * a[h*32 + c];
      fold[u] = sum;
    } else if (u < 48){
      int idx = u - 32; int j = idx & 7; int h = j>>1; int i = j&1;
      const float* a = (idx<8) ? as_d1 : ad_d1;
      float sum = 0.f;
      for (int c=0;c<32;c++) sum += w_d1[i*128 + h*32 + c] * a[h*32 + c];
      fold[32 + idx] = sum;
    }
  }
}

// ---------------- K2: partition pass — group edges by partition (chunk-exclusive runs) ----------------
__global__ __launch_bounds__(256) void partition_pass(const int* __restrict__ ei,
                                                      const int* __restrict__ pofs,
                                                      int2* __restrict__ pedge){
  __shared__ int cur[NP];
  for (int i=threadIdx.x; i<NP; i+=256) cur[i] = pofs[blockIdx.x*NP + i];
  __syncthreads();
  int base = blockIdx.x*EPC;
  int end = min(base+EPC, ET);
  for (int e = base+threadIdx.x; e < end; e += 256){
    int src, dst;
    if (e < E0){ src = ei[e]; dst = ei[E0+e]; } else { src = dst = e - E0; }
    int pos = atomicAdd(&cur[dst>>PBITS], 1);
    pedge[pos] = make_int2(src, dst);
  }
}

// ---------------- K3: per-partition LDS histogram + scan -> rowptr + exclusive-window scatter ----------------
__global__ __launch_bounds__(1024) void fine_build(const int2* __restrict__ pedge,
                                                   const int* __restrict__ pofs,
                                                   int* __restrict__ rowptr, int* __restrict__ ssrc){
  int p = blockIdx.x;
  int pstart = pofs[p];
  int pend = (p+1 < NP) ? pofs[p+1] : ET;
  int dbase = p << PBITS;
  __shared__ int hist[1<<PBITS];
  __shared__ int cur[1<<PBITS];
  int t = threadIdx.x;
  hist[t] = 0;
  __syncthreads();
  for (int i = pstart + t; i < pend; i += 1024)
    atomicAdd(&hist[pedge[i].y - dbase], 1);
  __syncthreads();
  int orig = hist[t];
  __syncthreads();
  int v = orig;
  for (int off=1; off<1024; off<<=1){
    int tmp = (t>=off) ? hist[t-off] : 0;
    __syncthreads();
    v += tmp; hist[t] = v; __syncthreads();
  }
  int excl = v - orig;
  int d = dbase + t;
  if (d < NN) rowptr[d] = pstart + excl;
  if (p == NP-1 && t == 0) rowptr[NN] = ET;
  cur[t] = pstart + excl;
  __syncthreads();
  for (int i = pstart + t; i < pend; i += 1024){
    int2 e = pedge[i];
    int pos = atomicAdd(&cur[e.y - dbase], 1);
    ssrc[pos] = e.x;
  }
}

// ---------------- node1: BN apply + layer-1 scores, packed write ----------------
// pk1[n*8]: [0..3]=als1 per head, [4..7]=xbn. ald1[n]: float4.
__global__ __launch_bounds__(256) void node1(
    const float* __restrict__ x, const float* __restrict__ sclsft, const float* __restrict__ fold,
    float* __restrict__ pk1, float* __restrict__ ald1){
  int n = blockIdx.x*256 + threadIdx.x;
  if (n >= NN) return;
  float4 v = reinterpret_cast<const float4*>(x)[n];
  float xb[4] = {v.x, v.y, v.z, v.w};
  #pragma unroll
  for (int i=0;i<4;i++) xb[i] = xb[i]*sclsft[i] + sclsft[4+i];
  float4 s4, d4;
  float* sp = &s4.x; float* dp = &d4.x;
  #pragma unroll
  for (int h=0;h<4;h++){
    float s=0.f, d=0.f;
    #pragma unroll
    for (int i=0;i<4;i++){ s += xb[i]*fold[h*4+i]; d += xb[i]*fold[16+h*4+i]; }
    sp[h]=s; dp[h]=d;
  }
  reinterpret_cast<float4*>(pk1)[n*2+0] = s4;
  reinterpret_cast<float4*>(pk1)[n*2+1] = make_float4(xb[0],xb[1],xb[2],xb[3]);
  reinterpret_cast<float4*>(ald1)[n] = d4;
}

// ---------------- 4-head edge aggregation: 8 lanes/dst = 2 edge-slots x 4 heads ----------------
// pk stride 8: [head]=als, [4..]=feat(NC). out[dst][head][NC] normalized.
template<int NC>
__global__ __launch_bounds__(256) void eagg_h4(
    const float* __restrict__ pk, const float* __restrict__ ald,
    const int* __restrict__ rowptr, const int* __restrict__ ssrc,
    float* __restrict__ out){
  int dst = blockIdx.x*32 + (threadIdx.x>>3);
  int sub = threadIdx.x & 7;
  if (dst >= NN) return;
  int eslot = sub>>2, head = sub&3;
  int r0 = rowptr[dst], r1 = rowptr[dst+1];
  float adv = ald[(size_t)dst*4 + head];
  float sum = 0.f, acc[NC];
  #pragma unroll
  for (int c=0;c<NC;c++) acc[c]=0.f;
  for (int i=r0+eslot; i<r1; i+=2){
    int s = ssrc[i];
    const float* base = pk + (size_t)s*8;
    float w = __expf(lrelu(base[head] + adv));
    sum += w;
    if constexpr (NC==4){
      float4 f = *reinterpret_cast<const float4*>(base+4);
      acc[0]+=w*f.x; acc[1]+=w*f.y; acc[2]+=w*f.z; acc[3]+=w*f.w;
    } else {
      float2 f = *reinterpret_cast<const float2*>(base+4);
      acc[0]+=w*f.x; acc[1]+=w*f.y;
    }
  }
  sum += __shfl_xor(sum, 4);
  #pragma unroll
  for (int c=0;c<NC;c++) acc[c] += __shfl_xor(acc[c], 4);
  if (eslot==0){
    float inv = 1.f/(sum+1e-16f);
    if constexpr (NC==4){
      reinterpret_cast<float4*>(out)[(size_t)dst*4 + head] =
        make_float4(acc[0]*inv, acc[1]*inv, acc[2]*inv, acc[3]*inv);
    } else {
      reinterpret_cast<float2*>(out)[(size_t)dst*4 + head] =
        make_float2(acc[0]*inv, acc[1]*inv);
    }
  }
}

// ---------------- 1-head edge aggregation: 8 lanes/dst ----------------
// EPI=2 (layer2): pk2 stride 4 {h2.x,h2.y,als2,-}; writes pk3 {als3[4],lat[2],-,-} + ald3
// EPI=4 (layer4): pk4 stride 8 {als4,-,-,-,h4[4]}; writes d_out
template<int NC, int STRIDE, int AOFF, int FOFF, int EPI>
__global__ __launch_bounds__(256) void eagg_h1(
    const float* __restrict__ pk, const float* __restrict__ ald,
    const int* __restrict__ rowptr, const int* __restrict__ ssrc,
    const float* __restrict__ bias, const float* __restrict__ fold,
    float* __restrict__ out, float* __restrict__ ald_out){
  int dst = blockIdx.x*32 + (threadIdx.x>>3);
  int sub = threadIdx.x & 7;
  if (dst >= NN) return;
  int r0 = rowptr[dst], r1 = rowptr[dst+1];
  float adv = ald[dst];
  float sum = 0.f, acc[NC];
  #pragma unroll
  for (int c=0;c<NC;c++) acc[c]=0.f;
  for (int i=r0+sub; i<r1; i+=8){
    int s = ssrc[i];
    const float* base = pk + (size_t)s*STRIDE;
    float w = __expf(lrelu(base[AOFF] + adv));
    sum += w;
    if constexpr (NC==2){
      float2 f = *reinterpret_cast<const float2*>(base+FOFF);
      acc[0]+=w*f.x; acc[1]+=w*f.y;
    } else {
      float4 f = *reinterpret_cast<const float4*>(base+FOFF);
      acc[0]+=w*f.x; acc[1]+=w*f.y; acc[2]+=w*f.z; acc[3]+=w*f.w;
    }
  }
  #pragma unroll
  for (int m=1;m<8;m<<=1){
    sum += __shfl_xor(sum,m);
    #pragma unroll
    for (int c=0;c<NC;c++) acc[c] += __shfl_xor(acc[c],m);
  }
  if (sub != 0) return;
  float inv = 1.f/(sum+1e-16f);
  if constexpr (EPI==2){
    float l0 = acc[0]*inv + bias[0];
    float l1 = acc[1]*inv + bias[1];
    float4 s3, d3; float* sp=&s3.x; float* dp=&d3.x;
    #pragma unroll
    for (int h=0;h<4;h++){
      sp[h] = l0*fold[32+h*2+0] + l1*fold[32+h*2+1];
      dp[h] = l0*fold[40+h*2+0] + l1*fold[40+h*2+1];
    }
    reinterpret_cast<float4*>(out)[(size_t)dst*2] = s3;
    out[(size_t)dst*8+4] = l0;
    out[(size_t)dst*8+5] = l1;
    reinterpret_cast<float4*>(ald_out)[dst] = d3;
  } else {
    reinterpret_cast<float4*>(out)[dst] =
      make_float4(acc[0]*inv+bias[0], acc[1]*inv+bias[1],
                  acc[2]*inv+bias[2], acc[3]*inv+bias[3]);
  }
}

// ---------------- post1: enc1 = relu(agg1 @ w_e1 + b) fused with layer-2 projection ----------------
__global__ __launch_bounds__(256) void post1(
    const float* __restrict__ agg1, const float* __restrict__ w_e1, const float* __restrict__ b_e1,
    const float* __restrict__ w_e3, const float* __restrict__ as_e3, const float* __restrict__ ad_e3,
    float* __restrict__ pk2, float* __restrict__ ald2){
  int lane = threadIdx.x & 63;
  int n = blockIdx.x*4 + (threadIdx.x>>6);
  int oc0 = lane, oc1 = lane + 64;
  int h0 = oc0>>5, h1 = oc1>>5;
  float4 a0 = reinterpret_cast<const float4*>(agg1)[n*4 + h0];
  float4 a1 = reinterpret_cast<const float4*>(agg1)[n*4 + h1];
  float e0 = b_e1[oc0] + a0.x*w_e1[0*128+oc0] + a0.y*w_e1[1*128+oc0]
                       + a0.z*w_e1[2*128+oc0] + a0.w*w_e1[3*128+oc0];
  float e1 = b_e1[oc1] + a1.x*w_e1[0*128+oc1] + a1.y*w_e1[1*128+oc1]
                       + a1.z*w_e1[2*128+oc1] + a1.w*w_e1[3*128+oc1];
  e0 = fmaxf(e0, 0.f); e1 = fmaxf(e1, 0.f);
  float p0 = e0*w_e3[oc0*2+0] + e1*w_e3[oc1*2+0];
  float p1 = e0*w_e3[oc0*2+1] + e1*w_e3[oc1*2+1];
  #pragma unroll
  for (int m=1;m<64;m<<=1){ p0 += __shfl_xor(p0,m); p1 += __shfl_xor(p1,m); }
  if (lane==0){
    reinterpret_cast<float4*>(pk2)[n] =
      make_float4(p0, p1, p0*as_e3[0]+p1*as_e3[1], 0.f);
    ald2[n] = p0*ad_e3[0] + p1*ad_e3[1];
  }
}

// ---------------- post3: dec1 = relu(agg3 @ w_d1 + b) fused with layer-4 projection ----------------
__global__ __launch_bounds__(256) void post3(
    const float* __restrict__ agg3, const float* __restrict__ w_d1, const float* __restrict__ b_d1,
    const float* __restrict__ w_d3, const float* __restrict__ as_d3, const float* __restrict__ ad_d3,
    float* __restrict__ pk4, float* __restrict__ ald4){
  int lane = threadIdx.x & 63;
  int n = blockIdx.x*4 + (threadIdx.x>>6);
  int oc0 = lane, oc1 = lane + 64;
  int h0 = oc0>>5, h1 = oc1>>5;
  float2 a0 = reinterpret_cast<const float2*>(agg3)[n*4 + h0];
  float2 a1 = reinterpret_cast<const float2*>(agg3)[n*4 + h1];
  float e0 = b_d1[oc0] + a0.x*w_d1[0*128+oc0] + a0.y*w_d1[1*128+oc0];
  float e1 = b_d1[oc1] + a1.x*w_d1[0*128+oc1] + a1.y*w_d1[1*128+oc1];
  e0 = fmaxf(e0, 0.f); e1 = fmaxf(e1, 0.f);
  float p[4];
  #pragma unroll
  for (int c=0;c<4;c++) p[c] = e0*w_d3[oc0*4+c] + e1*w_d3[oc1*4+c];
  #pragma unroll
  for (int m=1;m<64;m<<=1){
    #pragma unroll
    for (int c=0;c<4;c++) p[c] += __shfl_xor(p[c],m);
  }
  if (lane==0){
    float s=0.f, d=0.f;
    #pragma unroll
    for (int c=0;c<4;c++){ s += p[c]*as_d3[c]; d += p[c]*ad_d3[c]; }
    pk4[(size_t)n*8] = s;
    reinterpret_cast<float4*>(pk4 + (size_t)n*8 + 4)[0] = make_float4(p[0],p[1],p[2],p[3]);
    ald4[n] = d;
  }
}

// ---------------- launch ----------------
extern "C" void kernel_launch(void* const* d_in, const int* in_sizes, int n_in,
                              void* d_out, int out_size, void* d_ws, size_t ws_size,
                              hipStream_t stream) {
  const float* x     = (const float*)d_in[0];
  const int*   ei    = (const int*)  d_in[1];
  const float* gamma = (const float*)d_in[2];
  const float* beta  = (const float*)d_in[3];
  const float* w_e1  = (const float*)d_in[4];
  const float* as_e1 = (const float*)d_in[5];
  const float* ad_e1 = (const float*)d_in[6];
  const float* b_e1  = (const float*)d_in[7];
  const float* w_e3  = (const float*)d_in[8];
  const float* as_e3 = (const float*)d_in[9];
  const float* ad_e3 = (const float*)d_in[10];
  const float* b_e3  = (const float*)d_in[11];
  const float* w_d1  = (const float*)d_in[12];
  const float* as_d1 = (const float*)d_in[13];
  const float* ad_d1 = (const float*)d_in[14];
  const float* b_d1  = (const float*)d_in[15];
  const float* w_d3  = (const float*)d_in[16];
  const float* as_d3 = (const float*)d_in[17];
  const float* ad_d3 = (const float*)d_in[18];
  const float* b_d3  = (const float*)d_in[19];

  char* ws = (char*)d_ws;
  size_t off = 0;
  auto alloc = [&](size_t bytes)->void*{
    void* p = ws + off;
    off += (bytes + 255) & ~(size_t)255;
    return p;
  };
  int*   chunkcnt = (int*)  alloc((size_t)NCH*NP*4);
  int*   pofs     = (int*)  alloc((size_t)NCH*NP*4);
  int2*  pedge    = (int2*) alloc((size_t)ET*8);
  int*   rowptr   = (int*)  alloc((size_t)(NN+1)*4);
  int*   ssrc     = (int*)  alloc((size_t)ET*4);
  float* part     = (float*)alloc((size_t)NBP*8*4);
  float* sclsft   = (float*)alloc(32);
  float* fold     = (float*)alloc(64*4);
  float* pk1      = (float*)alloc((size_t)NN*8*4);
  float* ald1     = (float*)alloc((size_t)NN*4*4);
  float* agg1     = (float*)alloc((size_t)NN*16*4);
  float* pk2      = (float*)alloc((size_t)NN*4*4);
  float* ald2     = (float*)alloc((size_t)NN*4);
  float* pk3      = (float*)alloc((size_t)NN*8*4);
  float* ald3     = (float*)alloc((size_t)NN*4*4);
  float* agg3     = (float*)alloc((size_t)NN*8*4);
  float* pk4      = (float*)alloc((size_t)NN*8*4);
  float* ald4     = (float*)alloc((size_t)NN*4);

  // CSR build: deterministic two-level counting sort, block-exclusive write regions
  chunk_hist_bn<<<NCH, 256, 0, stream>>>(ei, chunkcnt, x, part);
  scan_fold<<<1, 1024, 0, stream>>>(chunkcnt, pofs, part, gamma, beta,
                                    w_e1, as_e1, ad_e1, w_d1, as_d1, ad_d1, sclsft, fold);
  partition_pass<<<NCH, 256, 0, stream>>>(ei, pofs, pedge);
  fine_build<<<NP, 1024, 0, stream>>>(pedge, pofs, rowptr, ssrc);

  const int AGG_BLOCKS = (NN+31)/32;

  // Layer 1
  node1<<<(NN+255)/256, 256, 0, stream>>>(x, sclsft, fold, pk1, ald1);
  eagg_h4<4><<<AGG_BLOCKS, 256, 0, stream>>>(pk1, ald1, rowptr, ssrc, agg1);
  post1<<<NN/4, 256, 0, stream>>>(agg1, w_e1, b_e1, w_e3, as_e3, ad_e3, pk2, ald2);
  // Layer 2 (fused layer-3 score projection)
  eagg_h1<2,4,2,0,2><<<AGG_BLOCKS, 256, 0, stream>>>(pk2, ald2, rowptr, ssrc, b_e3, fold, pk3, ald3);
  // Layer 3
  eagg_h4<2><<<AGG_BLOCKS, 256, 0, stream>>>(pk3, ald3, rowptr, ssrc, agg3);
  post3<<<NN/4, 256, 0, stream>>>(agg3, w_d1, b_d1, w_d3, as_d3, ad_d3, pk4, ald4);
  // Layer 4
  eagg_h1<4,8,0,4,4><<<AGG_BLOCKS, 256, 0, stream>>>(pk4, ald4, rowptr, ssrc, b_d3, nullptr, (float*)d_out, nullptr);
}